// Round 6
// baseline (352.051 us; speedup 1.0000x reference)
//
#include <hip/hip_runtime.h>
#include <math.h>

namespace {

constexpr int Bn = 16, Tn = 512, Dn = 768, Sn = 4, Hn = 48, On = 48;
constexpr int Mn = Bn * Tn;          // 8192 (b,t) rows
constexpr int Gn = Sn * Hn;          // 192 (s,h) groups
constexpr int Nn = Gn * On;          // 9216 flat N (= flat W rows)
constexpr float EMISS_W = 0.5f;

// workspace layout (float offsets), then bf16 regions ~27 MB
constexpr size_t OFF_LP   = 0;
constexpr size_t OFF_LT   = 64;
constexpr size_t OFF_PT   = OFF_LT + Hn*Hn;
constexpr size_t OFF_EM   = OFF_PT + Hn*Hn;
constexpr size_t OFF_LEPP = OFF_EM + (size_t)Sn*Hn*On;   // [m][g] g = s*48+h (log partials)
constexpr size_t OFF_LA   = OFF_LEPP + (size_t)Mn*Gn;    // alpha probs (per-t scale)
constexpr size_t OFF_LB   = OFF_LA + (size_t)Mn*Hn;      // beta probs (per-t scale)
constexpr size_t OFF_RED  = OFF_LB + (size_t)Mn*Hn;      // per-(b,t) partials [8192]
constexpr size_t FLOATS_END = OFF_RED + (size_t)Mn;

typedef __attribute__((ext_vector_type(8))) short short8;
typedef __attribute__((ext_vector_type(4))) float f32x4;

__device__ inline float waveSum(float v){
#pragma unroll
  for (int o = 32; o; o >>= 1) v += __shfl_xor(v, o);
  return v;
}

__device__ inline unsigned short f2bf(float f){
  unsigned int u = __float_as_uint(f);
  u += 0x7FFFu + ((u >> 16) & 1u);   // round-to-nearest-even
  return (unsigned short)(u >> 16);
}

__device__ inline void gload_lds16(const void* g, void* l){
  __builtin_amdgcn_global_load_lds(
      (const __attribute__((address_space(1))) void*)g,
      (__attribute__((address_space(3))) void*)l, 16, 0, 0);
}

// -------- conversion (all blocks but last) + param preprocessing (last block) --
__global__ void convprep_kernel(const float* __restrict__ srcA, unsigned short* __restrict__ dstA,
                                int n4a,
                                const float* __restrict__ srcB, unsigned short* __restrict__ dstB,
                                int n4b,
                                const float* __restrict__ sp, const float* __restrict__ ut,
                                const float* __restrict__ ue, float* __restrict__ ws,
                                int nconv){
  const int tid = threadIdx.x;
  if ((int)blockIdx.x == nconv){
    // ---- prep ----
    float m = -INFINITY;
    for (int h = 0; h < Hn; ++h) m = fmaxf(m, sp[h]);
    float s = 0.f;
    for (int h = 0; h < Hn; ++h) s += __expf(sp[h] - m);
    float lse = m + __logf(s);
    if (tid < Hn) ws[OFF_LP + tid] = sp[tid] - lse;
    if (tid < Hn){
      const float* row = ut + tid * Hn;
      float mm = -INFINITY;
      for (int j = 0; j < Hn; ++j) mm = fmaxf(mm, row[j]);
      float ss = 0.f;
      for (int j = 0; j < Hn; ++j) ss += __expf(row[j] - mm);
      float l = mm + __logf(ss);
      for (int j = 0; j < Hn; ++j){
        float v = row[j] - l;
        ws[OFF_LT + tid*Hn + j] = v;
        ws[OFF_PT + tid*Hn + j] = __expf(v);
      }
    }
    for (int r = tid; r < Sn*Hn; r += blockDim.x){
      const float* row = ue + (size_t)r * On;
      float mm = -INFINITY;
      for (int o = 0; o < On; ++o) mm = fmaxf(mm, row[o]);
      float ss = 0.f;
      for (int o = 0; o < On; ++o) ss += __expf(row[o] - mm);
      float inv = 1.f/ss;
      for (int o = 0; o < On; ++o) ws[OFF_EM + (size_t)r*On + o] = __expf(row[o]-mm)*inv;
    }
    return;
  }
  // ---- conv ----
  int i = blockIdx.x * blockDim.x + tid;
  const float* s2; unsigned short* d; int k;
  if (i < n4a){ s2 = srcA; d = dstA; k = i; }
  else { k = i - n4a; if (k >= n4b) return; s2 = srcB; d = dstB; }
  float4 v = ((const float4*)s2)[k];
  ushort4 r;
  r.x = f2bf(v.x); r.y = f2bf(v.y); r.z = f2bf(v.z); r.w = f2bf(v.w);
  ((ushort4*)d)[k] = r;
}

// ---------------- bf16 MFMA GEMM + fused softmax/mix/obs-dot epilogue ----------
// R15: A out of LDS entirely. R10-R14 showed co-resident blocks phase-lock
// (in-phase is self-stabilizing on the shared LDS port) so LDS+MFMA windows
// serialize: floors were LDS 56us + MFMA 56us = the ~129us fixed point.
// A fragments load DIRECTLY global->reg: 16x16x32 A-frag = lane(lm,q) ->
// 16B contiguous at A[row][kk*32+q*8]; 4-lane q-groups cover full 64B
// segments; all L2-hits (A slab 3.1MB/XCD resident, verified R11-R14).
// LDS-read floor drops 56->34us (B-only, 12 reads/wave/tile). A regs
// double-buffered 1 tile ahead (aA/aB, static indexing), addressed by 4
// per-mb base pointers + imm offsets (zero per-tile VALU). B path, swizzle,
// epilogue, slab swizzle unchanged from R14. setprio dropped (m190).
// LDS 51200 B (B dbuf 49152 + epilogue tables), still 2 blocks/CU.
constexpr int BM = 128, BN = 192, BK = 64;
constexpr int NKT = Dn / BK;         // 12 K-tiles
// LDS byte map: B[2] @ 0 (2x24576); epilogue C-park + tables alias after.

__global__ __launch_bounds__(256, 2) void gemm_lep_kernel(
    const unsigned short* __restrict__ embB, const unsigned short* __restrict__ WB,
    const float* __restrict__ bm, const float* __restrict__ obs,
    float* __restrict__ ws){
  __shared__ __align__(16) char smem[51200];
  const int tid = threadIdx.x, lane = tid & 63, w = tid >> 6;   // w 0..3
  // XCD slab swizzle: 3072 blocks. XCD x owns m-quarter (x&3) x N-half (x>>2);
  // inner loop over m (16 m-tiles, A slab 3.1MB L2-resident), outer over n.
  const int bid = blockIdx.y * (Mn/BM) + blockIdx.x;
  const int xcd = bid & 7, j_loc = bid >> 3;     // j_loc in [0,384)
  const int xm = xcd & 3, xn = xcd >> 2;
  const int mloc = j_loc & 15, nloc = j_loc >> 4; // 16 m-tiles, 24 n-panels
  const int m0 = (xm*16 + mloc) * BM;             // m-tile 0..63
  const int by = xn*24 + nloc;                    // N-panel 0..47
  const int N0 = by * BN;
  const int wm = w & 1, wn = w >> 1;           // 2 x 2 wave grid
  const int lm = lane & 15, q = lane >> 4;
  const int key = lm & 7;
  const int srow = lane >> 3, spc = lane & 7;
  const int aoff0 = (q ^ key) << 4;            // kk=0 chunk byte offset (B)
  const int aoff1 = ((4 + q) ^ key) << 4;      // kk=1

  f32x4 acc[4][6];
#pragma unroll
  for (int i = 0; i < 4; ++i)
#pragma unroll
    for (int j = 0; j < 6; ++j) acc[i][j] = (f32x4){0.f,0.f,0.f,0.f};

  // A direct-load base pointers, one per 16-row m-block (advance 64 elems/tile)
  const unsigned short* aP[4];
#pragma unroll
  for (int mb = 0; mb < 4; ++mb)
    aP[mb] = embB + (size_t)(m0 + wm*64 + mb*16 + lm)*Dn + q*8;

  auto stageB = [&](int kt, int i){            // i = 0..5 -> 192 rows
    const int idx = w*6 + i;                   // 0..23
    const int row = idx*8 + srow;
    const int lc  = spc ^ (row & 7);
    gload_lds16(WB + (size_t)(N0+row)*Dn + kt*BK + lc*8,
                smem + (kt & 1)*24576 + idx*1024);
  };

  short8 aA[4][2], aB[4][2];

  // prologue: A tile 0 -> aA; stage B tile 0 (gate in loop waits both)
#pragma unroll
  for (int mb = 0; mb < 4; ++mb){
    aA[mb][0] = *(const short8*)(aP[mb]);
    aA[mb][1] = *(const short8*)(aP[mb] + 32);
  }
#pragma unroll
  for (int mb = 0; mb < 4; ++mb) aP[mb] += BK;
#pragma unroll
  for (int i = 0; i < 6; ++i) stageB(0, i);

  auto TILE = [&](int kt, short8 (&CUR)[4][2], short8 (&NXT)[4][2]){
    // gate: A(kt) regs + B-stage(kt) landed (issued a full tile ago)
    asm volatile("s_waitcnt vmcnt(0)" ::: "memory");
    asm volatile("s_barrier" ::: "memory");
    const int pf = kt + 1;
    // A prefetch for tile kt+1 -> NXT (8 x global_load_dwordx4, L2-hit)
    if (pf < NKT){
#pragma unroll
      for (int mb = 0; mb < 4; ++mb){
        NXT[mb][0] = *(const short8*)(aP[mb]);
        NXT[mb][1] = *(const short8*)(aP[mb] + 32);
      }
    }
#pragma unroll
    for (int mb = 0; mb < 4; ++mb) aP[mb] += BK;
    // B fragment reads (FIFO: kk0 first -> compiler counts lgkm per cluster)
    const char* Bb = smem + (kt & 1)*24576;
    short8 bf0[6], bf1[6];
#pragma unroll
    for (int j = 0; j < 6; ++j)
      bf0[j] = *(const short8*)(Bb + (wn*96 + j*16 + lm)*128 + aoff0);
#pragma unroll
    for (int j = 0; j < 6; ++j)
      bf1[j] = *(const short8*)(Bb + (wn*96 + j*16 + lm)*128 + aoff1);
    // stage B for tile kt+1 into the opposite buffer
    if (pf < NKT){
#pragma unroll
      for (int i = 0; i < 6; ++i) stageB(pf, i);
    }
    // MFMA: 24 per kk, A from registers (no LDS dependency)
#pragma unroll
    for (int i = 0; i < 4; ++i)
#pragma unroll
      for (int j = 0; j < 6; ++j)
        acc[i][j] = __builtin_amdgcn_mfma_f32_16x16x32_bf16(CUR[i][0], bf0[j], acc[i][j], 0, 0, 0);
#pragma unroll
    for (int i = 0; i < 4; ++i)
#pragma unroll
      for (int j = 0; j < 6; ++j)
        acc[i][j] = __builtin_amdgcn_mfma_f32_16x16x32_bf16(CUR[i][1], bf1[j], acc[i][j], 0, 0, 0);
  };

  for (int kt = 0; kt < NKT; kt += 2){
    TILE(kt,     aA, aB);
    TILE(kt + 1, aB, aA);
  }

  // ---- epilogue: park C (64 rows x stride 193) + bias/em tables over dead
  //      staging; fused softmax / mix / obs-dot / log. 2 halves of 64 rows;
  //      each half parked by the 2 waves owning it, computed by all 256
  //      threads (64 rows x 4 groups).
  __syncthreads();   // all waves done reading smem before C-park overwrites
  float* Cp  = (float*)smem;
  float* ext = (float*)(smem + 49408);   // bias [0..191], em [192..383]
  if (tid < 192){
    ext[tid]       = bm[N0 + tid];
    ext[192 + tid] = ws[OFF_EM + N0 + tid];
  }
#pragma unroll
  for (int h = 0; h < 2; ++h){
    if (h) __syncthreads();
    if (wm == h){
#pragma unroll
      for (int i = 0; i < 4; ++i)
#pragma unroll
        for (int j = 0; j < 6; ++j){
          const int col = wn*96 + j*16 + lm;
#pragma unroll
          for (int r = 0; r < 4; ++r){
            const int rowl = i*16 + q*4 + r;
            Cp[rowl*193 + col] = acc[i][j][r];
          }
        }
    }
    __syncthreads();
    {
      const int rowl = tid >> 2, grp = tid & 3;
      const int m = m0 + h*64 + rowl;
      const int g = by*4 + grp;
      const int s2 = g / Hn;                   // constant per block
      const float* crow = Cp + rowl*193 + grp*48;
      const float* ob   = obs + ((size_t)m*Sn + s2)*On;
      const float* bi   = ext + grp*48;
      const float* em   = ext + 192 + grp*48;
      float Z = 0.f, pd = 0.f, eo = 0.f;
#pragma unroll
      for (int o = 0; o < On; ++o){
        float e = __expf(crow[o] + bi[o]);
        float obv = ob[o];
        Z += e;
        pd = fmaf(e, obv, pd);
        eo = fmaf(em[o], obv, eo);
      }
      ws[OFF_LEPP + (size_t)m*Gn + g] = __logf((1.f-EMISS_W)*eo + EMISS_W*(pd/Z));
    }
  }
}

// ---------------- forward/backward recursions: chunked with warm-up ----------
// Serial depth 40 (FBW warm-up + FBL chunk). Stages exp(sum of 4 lep
// partials) straight from OFF_LEPP (lep_reduce kernel deleted).
constexpr int FBW = 24;   // warm-up steps
constexpr int FBL = 16;   // chunk length

__global__ __launch_bounds__(64) void fb_kernel(float* __restrict__ ws){
  __shared__ __align__(16) float ldsE[(FBW+FBL)*48];   // exp(lep) window
  __shared__ __align__(16) float ring[2][64];
  const int lane = threadIdx.x;
  const int c    = blockIdx.x;
  const int b    = blockIdx.y;
  const bool fwd = blockIdx.z == 0;
  const bool act = lane < Hn;
  const int t0 = c*FBL, te = t0 + FBL - 1;

  float pt[Hn];
#pragma unroll
  for (int i = 0; i < Hn; ++i)
    pt[i] = act ? (fwd ? ws[OFF_PT + i*Hn + lane] : ws[OFF_PT + lane*Hn + i]) : 0.f;

  int row_lo, nrows, sA, sZ;
  bool exact;
  if (fwd){
    sA = t0 - FBW;
    exact = (sA < 1);
    row_lo = exact ? 0 : sA;
    if (exact) sA = 1;
    sZ = te;
    nrows = te - row_lo + 1;
  } else {
    int th = te + 1 + FBW;
    exact = (th > Tn - 2);
    sA = exact ? Tn - 2 : th - 1;
    sZ = t0;
    row_lo = t0;
    nrows = sA - t0 + 1;
  }

  // stage exp(lep) = exp(sum of 4 partials) from [m][192] layout
  {
    const float* src = ws + OFF_LEPP + ((size_t)b*Tn + row_lo)*Gn;
    int n4 = nrows * (Hn/4);
    for (int i = lane; i < n4; i += 64){
      int r = i / (Hn/4), h4 = i - r*(Hn/4);
      const float* p = src + (size_t)r*Gn + h4*4;
      float4 a = *(const float4*)(p);
      float4 b2 = *(const float4*)(p + Hn);
      float4 c2 = *(const float4*)(p + 2*Hn);
      float4 d2 = *(const float4*)(p + 3*Hn);
      float4 e;
      e.x = __expf(a.x + b2.x + c2.x + d2.x);
      e.y = __expf(a.y + b2.y + c2.y + d2.y);
      e.z = __expf(a.z + b2.z + c2.z + d2.z);
      e.w = __expf(a.w + b2.w + c2.w + d2.w);
      ((float4*)ldsE)[i] = e;
    }
  }
  __syncthreads();

  if (fwd){
    const size_t laF = OFF_LA + (size_t)b * Tn * Hn;
    float v;
    if (exact){
      v = act ? __expf(ws[OFF_LP + lane]) * ldsE[lane] : 0.f;   // alpha_0
      if (c == 0 && act) ws[laF + lane] = v;
    } else {
      v = act ? 1.f : 0.f;
    }
    if (act) ring[0][lane] = v;
    __syncthreads();
    int cur = 0;
    for (int t = sA; t <= sZ; ++t){
      float S = waveSum(v);
      const float* rp = ring[cur];
      float s0=0.f,s1=0.f,s2=0.f,s3=0.f;
#pragma unroll
      for (int i = 0; i < Hn; i += 4){
        float4 a = *(const float4*)(rp + i);
        s0 = fmaf(a.x, pt[i+0], s0); s1 = fmaf(a.y, pt[i+1], s1);
        s2 = fmaf(a.z, pt[i+2], s2); s3 = fmaf(a.w, pt[i+3], s3);
      }
      float sd = (s0+s1)+(s2+s3);
      float e = act ? ldsE[(t - row_lo)*Hn + lane] : 0.f;
      float vn = act ? e * sd * (1.f/S) : 0.f;
      cur ^= 1;
      if (act) ring[cur][lane] = vn;
      __syncthreads();
      if (act && t >= t0) ws[laF + (size_t)t*Hn + lane] = vn;
      v = vn;
    }
  } else {
    const size_t lbF = OFF_LB + (size_t)b * Tn * Hn;
    float v = act ? 1.f : 0.f;
    if (exact && c == (Tn/FBL - 1) && act) ws[lbF + (size_t)(Tn-1)*Hn + lane] = 1.f;
    int cur = 0;
    for (int t = sA; t >= sZ; --t){
      float e = act ? ldsE[(t - row_lo)*Hn + lane] : 0.f;
      float wv = e * v;
      if (act) ring[cur][lane] = wv;
      float S = waveSum(wv);
      __syncthreads();
      const float* rp = ring[cur];
      float s0=0.f,s1=0.f,s2=0.f,s3=0.f;
#pragma unroll
      for (int j = 0; j < Hn; j += 4){
        float4 a = *(const float4*)(rp + j);
        s0 = fmaf(a.x, pt[j+0], s0); s1 = fmaf(a.y, pt[j+1], s1);
        s2 = fmaf(a.z, pt[j+2], s2); s3 = fmaf(a.w, pt[j+3], s3);
      }
      float vn = act ? ((s0+s1)+(s2+s3)) * (1.f/S) : 0.f;
      cur ^= 1;
      if (act && t <= te) ws[lbF + (size_t)t*Hn + lane] = vn;
      v = vn;
    }
  }
}

// -------- gamma / xi / masked accumulation (prob domain, no atomics) -----------
// One coalesced partial store per block; sum_kernel reduces. (R9's last-block
// counter pattern = 8192 serialized same-address atomics+fences = 165us. Never
// funnel per-block completion through one address on this chip.)
__global__ __launch_bounds__(256) void gamma_xi_kernel(
    const float* __restrict__ ws_c, float* __restrict__ ws,
    const int* __restrict__ seq_len){
  __shared__ float y_s[Hn], lap_s[Hn];
  __shared__ float red[8];
  const int tid = threadIdx.x;
  const int bid = blockIdx.x;
  const int b = bid >> 9, t = bid & (Tn-1);
  const int len = seq_len[b];
  int tb = t + (Tn - len); if (tb >= Tn) tb -= Tn;
  const size_t bt = (size_t)b*Tn + t;
  float lep = 0.f;
  if (tid < Hn){
    const float* lpp = ws_c + OFF_LEPP + bt*Gn + tid;
    lep = lpp[0] + lpp[Hn] + lpp[2*Hn] + lpp[3*Hn];
    float lb  = ws_c[OFF_LB + ((size_t)b*Tn + tb)*Hn + tid];
    y_s[tid] = __expf(lep) * lb;
    if (t >= 1) lap_s[tid] = ws_c[OFF_LA + (bt-1)*Hn + tid];
  }
  float emis_term = 0.f, prior_term = 0.f;
  if (tid < 64){
    int h = (tid < Hn) ? tid : 0;
    float la  = ws_c[OFF_LA + bt*Hn + h];
    float lb  = ws_c[OFF_LB + ((size_t)b*Tn + tb)*Hn + h];
    float lp  = ws_c[OFF_LP + h];
    float wgt = (tid < Hn) ? la*lb : 0.f;
    float Z = waveSum(wgt);
    float inv = 1.f / Z;
    emis_term  = waveSum(wgt * lep) * inv;
    prior_term = waveSum(wgt * lp) * inv;
  }
  __syncthreads();
  float tran_term = 0.f;
  if (t >= 1){
    float se = 0.f, st = 0.f;
#pragma unroll
    for (int k=0;k<9;++k){
      int e = tid + k*256;
      int i = e / Hn, j = e - i*Hn;
      float e2 = ws_c[OFF_PT + e] * lap_s[i] * y_s[j];
      se += e2;
      st = fmaf(e2, ws_c[OFF_LT + e], st);
    }
    se = waveSum(se);
    st = waveSum(st);
    const int wid = tid >> 6;
    if ((tid & 63) == 0){ red[wid] = se; red[4+wid] = st; }
    __syncthreads();
    if (tid == 0){
      float SE = red[0]+red[1]+red[2]+red[3];
      float ST = red[4]+red[5]+red[6]+red[7];
      tran_term = ST / SE;
    }
  }
  if (tid == 0){
    float tot = 0.f;
    if (t < len)            tot += emis_term;
    if (t == 0)             tot += prior_term;
    if (t >= 1 && t < len)  tot += tran_term;
    ws[OFF_RED + bid] = tot;
  }
}

// ---------------- final reduction: 8192 partials -> scalar ---------------------
__global__ __launch_bounds__(256) void sum_kernel(const float* __restrict__ ws,
                                                  float* __restrict__ out){
  __shared__ float red[4];
  const int tid = threadIdx.x;
  float s = 0.f;
  for (int i = tid; i < Mn; i += 256) s += ws[OFF_RED + i];
  s = waveSum(s);
  if ((tid & 63) == 0) red[tid >> 6] = s;
  __syncthreads();
  if (tid == 0) out[0] = (red[0]+red[1]+red[2]+red[3]) * (1.f / Bn);
}

} // namespace

extern "C" void kernel_launch(void* const* d_in, const int* in_sizes, int n_in,
                              void* d_out, int out_size, void* d_ws, size_t ws_size,
                              hipStream_t stream){
  const float* emb = (const float*)d_in[0];
  const float* obs = (const float*)d_in[1];
  const float* sp  = (const float*)d_in[2];
  const float* ut  = (const float*)d_in[3];
  const float* ue  = (const float*)d_in[4];
  const float* Wm  = (const float*)d_in[5];
  const float* bm  = (const float*)d_in[6];
  const int*   sl  = (const int*)d_in[7];
  float* ws  = (float*)d_ws;
  float* out = (float*)d_out;
  (void)in_sizes; (void)n_in; (void)ws_size; (void)out_size;

  unsigned short* embB = (unsigned short*)(ws + FLOATS_END);
  unsigned short* WB   = embB + (size_t)Mn * Dn;

  const int n4a = Mn*Dn/4, n4b = Nn*Dn/4;
  const int nconv = (n4a + n4b + 255)/256;
  convprep_kernel<<<nconv + 1, 256, 0, stream>>>(emb, embB, n4a, Wm, WB, n4b,
                                                 sp, ut, ue, ws, nconv);
  gemm_lep_kernel<<<dim3(Mn/BM, Nn/BN), 256, 0, stream>>>(embB, WB, bm, obs, ws);
  fb_kernel<<<dim3(Tn/FBL, Bn, 2), 64, 0, stream>>>(ws);
  gamma_xi_kernel<<<Bn*Tn, 256, 0, stream>>>(ws, ws, sl);
  sum_kernel<<<1, 256, 0, stream>>>(ws, out);
}

// Round 7
// 291.688 us; speedup vs baseline: 1.2069x; 1.2069x over previous
//
#include <hip/hip_runtime.h>
#include <math.h>

namespace {

constexpr int Bn = 16, Tn = 512, Dn = 768, Sn = 4, Hn = 48, On = 48;
constexpr int Mn = Bn * Tn;          // 8192 (b,t) rows
constexpr int Gn = Sn * Hn;          // 192 (s,h) groups
constexpr int Nn = Gn * On;          // 9216 flat N (= flat W rows)
constexpr float EMISS_W = 0.5f;

// workspace layout (float offsets), then bf16 regions ~27 MB
constexpr size_t OFF_LP   = 0;
constexpr size_t OFF_LT   = 64;
constexpr size_t OFF_PT   = OFF_LT + Hn*Hn;
constexpr size_t OFF_EM   = OFF_PT + Hn*Hn;
constexpr size_t OFF_LEPP = OFF_EM + (size_t)Sn*Hn*On;   // [m][g] g = s*48+h (log partials)
constexpr size_t OFF_LA   = OFF_LEPP + (size_t)Mn*Gn;    // alpha probs (per-t scale)
constexpr size_t OFF_LB   = OFF_LA + (size_t)Mn*Hn;      // beta probs (per-t scale)
constexpr size_t OFF_RED  = OFF_LB + (size_t)Mn*Hn;      // per-(b,t) partials [8192]
constexpr size_t FLOATS_END = OFF_RED + (size_t)Mn;

typedef __attribute__((ext_vector_type(8))) short short8;
typedef __attribute__((ext_vector_type(4))) float f32x4;

__device__ inline float waveSum(float v){
#pragma unroll
  for (int o = 32; o; o >>= 1) v += __shfl_xor(v, o);
  return v;
}

__device__ inline unsigned short f2bf(float f){
  unsigned int u = __float_as_uint(f);
  u += 0x7FFFu + ((u >> 16) & 1u);   // round-to-nearest-even
  return (unsigned short)(u >> 16);
}

__device__ inline void gload_lds16(const void* g, void* l){
  __builtin_amdgcn_global_load_lds(
      (const __attribute__((address_space(1))) void*)g,
      (__attribute__((address_space(3))) void*)l, 16, 0, 0);
}

// -------- conversion (all blocks but last) + param preprocessing (last block) --
__global__ void convprep_kernel(const float* __restrict__ srcA, unsigned short* __restrict__ dstA,
                                int n4a,
                                const float* __restrict__ srcB, unsigned short* __restrict__ dstB,
                                int n4b,
                                const float* __restrict__ sp, const float* __restrict__ ut,
                                const float* __restrict__ ue, float* __restrict__ ws,
                                int nconv){
  const int tid = threadIdx.x;
  if ((int)blockIdx.x == nconv){
    // ---- prep ----
    float m = -INFINITY;
    for (int h = 0; h < Hn; ++h) m = fmaxf(m, sp[h]);
    float s = 0.f;
    for (int h = 0; h < Hn; ++h) s += __expf(sp[h] - m);
    float lse = m + __logf(s);
    if (tid < Hn) ws[OFF_LP + tid] = sp[tid] - lse;
    if (tid < Hn){
      const float* row = ut + tid * Hn;
      float mm = -INFINITY;
      for (int j = 0; j < Hn; ++j) mm = fmaxf(mm, row[j]);
      float ss = 0.f;
      for (int j = 0; j < Hn; ++j) ss += __expf(row[j] - mm);
      float l = mm + __logf(ss);
      for (int j = 0; j < Hn; ++j){
        float v = row[j] - l;
        ws[OFF_LT + tid*Hn + j] = v;
        ws[OFF_PT + tid*Hn + j] = __expf(v);
      }
    }
    for (int r = tid; r < Sn*Hn; r += blockDim.x){
      const float* row = ue + (size_t)r * On;
      float mm = -INFINITY;
      for (int o = 0; o < On; ++o) mm = fmaxf(mm, row[o]);
      float ss = 0.f;
      for (int o = 0; o < On; ++o) ss += __expf(row[o] - mm);
      float inv = 1.f/ss;
      for (int o = 0; o < On; ++o) ws[OFF_EM + (size_t)r*On + o] = __expf(row[o]-mm)*inv;
    }
    return;
  }
  // ---- conv ----
  int i = blockIdx.x * blockDim.x + tid;
  const float* s2; unsigned short* d; int k;
  if (i < n4a){ s2 = srcA; d = dstA; k = i; }
  else { k = i - n4a; if (k >= n4b) return; s2 = srcB; d = dstB; }
  float4 v = ((const float4*)s2)[k];
  ushort4 r;
  r.x = f2bf(v.x); r.y = f2bf(v.y); r.z = f2bf(v.z); r.w = f2bf(v.w);
  ((ushort4*)d)[k] = r;
}

// ---------------- bf16 MFMA GEMM + fused softmax/mix/obs-dot epilogue ----------
// R16: true counted-vmcnt depth-2 pipeline (T4). R15's A-direct-load was
// TA-request-bound (16 segments/instr) -> reverted to gload_lds staging.
// R14's residual stall: vmcnt(0) gate drains stage loads with only ~300-500cy
// cover; ~16% L2 misses (900cy) stall every tile. Fix: BK 64->32 (24 tiles),
// TRIPLE buffer (A 3x8K + B 3x12K = 61440B, still 2 blocks/CU). Steady state:
// tile t stages tile t+2 into buf (t+2)%3 (free: t-1 consumed, gate barrier
// guarantees); gate waits vmcnt(5) -- drains tile t's 5 loads (issued 2 tiles
// ~700+cy earlier), keeps t+1's 5 in flight. Never drains to 0 until the
// tail (m218: counted-vs-drain0 = +38-73%). One barrier + one counted wait
// per tile; per-wave vmcnt before barrier => all waves' stages visible.
// Fragment math re-derived for BK=32: 4 16B-chunks/row, read key lm&3,
// stage swizzle lc = spc ^ (srow&3). Slab swizzle + epilogue unchanged.
constexpr int BM = 128, BN = 192, BK = 32;
constexpr int NKT = Dn / BK;         // 24 K-tiles
// LDS byte map: A[3] @ 0 (3x8192), B[3] @ 24576 (3x12288), total 61440.

__global__ __launch_bounds__(256, 2) void gemm_lep_kernel(
    const unsigned short* __restrict__ embB, const unsigned short* __restrict__ WB,
    const float* __restrict__ bm, const float* __restrict__ obs,
    float* __restrict__ ws){
  __shared__ __align__(16) char smem[61440];
  const int tid = threadIdx.x, lane = tid & 63, w = tid >> 6;   // w 0..3
  // XCD slab swizzle: 3072 blocks. XCD x owns m-quarter (x&3) x N-half (x>>2);
  // inner loop over m (16 m-tiles, A slab 3.1MB L2-resident), outer over n.
  const int bid = blockIdx.y * (Mn/BM) + blockIdx.x;
  const int xcd = bid & 7, j_loc = bid >> 3;     // j_loc in [0,384)
  const int xm = xcd & 3, xn = xcd >> 2;
  const int mloc = j_loc & 15, nloc = j_loc >> 4; // 16 m-tiles, 24 n-panels
  const int m0 = (xm*16 + mloc) * BM;             // m-tile 0..63
  const int by = xn*24 + nloc;                    // N-panel 0..47
  const int N0 = by * BN;
  const int wm = w & 1, wn = w >> 1;           // 2 x 2 wave grid
  const int lm = lane & 15, q = lane >> 4;
  const int aoff = ((q ^ (lm & 3)) << 4);      // read chunk byte offset (A & B)
  const int srow = lane >> 2, spc = lane & 3;  // stage: 4 threads/row (64B)

  f32x4 acc[4][6];
#pragma unroll
  for (int i = 0; i < 4; ++i)
#pragma unroll
    for (int j = 0; j < 6; ++j) acc[i][j] = (f32x4){0.f,0.f,0.f,0.f};

  auto stageA = [&](int kt, int R, int i){     // i = 0..1 -> 128 rows
    const int idx = w*2 + i;                   // 0..7, 16 rows each
    const int row = idx*16 + srow;
    const int lc  = spc ^ (srow & 3);          // == spc ^ (row&3)
    gload_lds16(embB + (size_t)(m0+row)*Dn + kt*BK + lc*8,
                smem + R*8192 + idx*1024);
  };
  auto stageB = [&](int kt, int R, int i){     // i = 0..2 -> 192 rows
    const int idx = w*3 + i;                   // 0..11, 16 rows each
    const int row = idx*16 + srow;
    const int lc  = spc ^ (srow & 3);
    gload_lds16(WB + (size_t)(N0+row)*Dn + kt*BK + lc*8,
                smem + 24576 + R*12288 + idx*1024);
  };

  auto TILE = [&](int kt, int R){
    const int Rpf = (R + 2) % 3;               // R literal -> folds
    // gate: own tile-kt stages landed (issued 2 tiles ago); keep t+1 in flight
    if (kt < NKT-1) asm volatile("s_waitcnt vmcnt(5)" ::: "memory");
    else            asm volatile("s_waitcnt vmcnt(0)" ::: "memory");
    asm volatile("s_barrier" ::: "memory");
    // 10 ds_read_b128 (compiler counts lgkm per MFMA cluster)
    const char* Ab = smem + R*8192;
    const char* Bb = smem + 24576 + R*12288;
    short8 af[4], bf[6];
#pragma unroll
    for (int j = 0; j < 6; ++j)
      bf[j] = *(const short8*)(Bb + (wn*96 + j*16 + lm)*64 + aoff);
#pragma unroll
    for (int i = 0; i < 4; ++i)
      af[i] = *(const short8*)(Ab + (wm*64 + i*16 + lm)*64 + aoff);
    // stage tile kt+2 into buffer (R+2)%3 (tile kt-1's buffer, consumed)
    const int pf = kt + 2;
    if (pf < NKT){
      stageA(pf, Rpf, 0); stageA(pf, Rpf, 1);
      stageB(pf, Rpf, 0); stageB(pf, Rpf, 1); stageB(pf, Rpf, 2);
    }
    // 24 MFMA (K=32 each)
#pragma unroll
    for (int i = 0; i < 4; ++i)
#pragma unroll
      for (int j = 0; j < 6; ++j)
        acc[i][j] = __builtin_amdgcn_mfma_f32_16x16x32_bf16(af[i], bf[j], acc[i][j], 0, 0, 0);
  };

  // prologue: stage tiles 0 and 1 (10 loads outstanding)
  stageA(0,0,0); stageA(0,0,1); stageB(0,0,0); stageB(0,0,1); stageB(0,0,2);
  stageA(1,1,0); stageA(1,1,1); stageB(1,1,0); stageB(1,1,1); stageB(1,1,2);

  for (int kt = 0; kt < NKT; kt += 3){
    TILE(kt,     0);
    TILE(kt + 1, 1);
    TILE(kt + 2, 2);
  }

  // ---- epilogue: park C (64 rows x stride 193) + bias/em tables over dead
  //      staging; fused softmax / mix / obs-dot / log. 2 halves of 64 rows;
  //      each half parked by the 2 waves owning it, computed by all 256
  //      threads (64 rows x 4 groups).
  __syncthreads();   // all waves done reading smem before C-park overwrites
  float* Cp  = (float*)smem;
  float* ext = (float*)(smem + 49408);   // bias [0..191], em [192..383]
  if (tid < 192){
    ext[tid]       = bm[N0 + tid];
    ext[192 + tid] = ws[OFF_EM + N0 + tid];
  }
#pragma unroll
  for (int h = 0; h < 2; ++h){
    if (h) __syncthreads();
    if (wm == h){
#pragma unroll
      for (int i = 0; i < 4; ++i)
#pragma unroll
        for (int j = 0; j < 6; ++j){
          const int col = wn*96 + j*16 + lm;
#pragma unroll
          for (int r = 0; r < 4; ++r){
            const int rowl = i*16 + q*4 + r;
            Cp[rowl*193 + col] = acc[i][j][r];
          }
        }
    }
    __syncthreads();
    {
      const int rowl = tid >> 2, grp = tid & 3;
      const int m = m0 + h*64 + rowl;
      const int g = by*4 + grp;
      const int s2 = g / Hn;                   // constant per block
      const float* crow = Cp + rowl*193 + grp*48;
      const float* ob   = obs + ((size_t)m*Sn + s2)*On;
      const float* bi   = ext + grp*48;
      const float* em   = ext + 192 + grp*48;
      float Z = 0.f, pd = 0.f, eo = 0.f;
#pragma unroll
      for (int o = 0; o < On; ++o){
        float e = __expf(crow[o] + bi[o]);
        float obv = ob[o];
        Z += e;
        pd = fmaf(e, obv, pd);
        eo = fmaf(em[o], obv, eo);
      }
      ws[OFF_LEPP + (size_t)m*Gn + g] = __logf((1.f-EMISS_W)*eo + EMISS_W*(pd/Z));
    }
  }
}

// ---------------- forward/backward recursions: chunked with warm-up ----------
// Serial depth 40 (FBW warm-up + FBL chunk). Stages exp(sum of 4 lep
// partials) straight from OFF_LEPP (lep_reduce kernel deleted).
constexpr int FBW = 24;   // warm-up steps
constexpr int FBL = 16;   // chunk length

__global__ __launch_bounds__(64) void fb_kernel(float* __restrict__ ws){
  __shared__ __align__(16) float ldsE[(FBW+FBL)*48];   // exp(lep) window
  __shared__ __align__(16) float ring[2][64];
  const int lane = threadIdx.x;
  const int c    = blockIdx.x;
  const int b    = blockIdx.y;
  const bool fwd = blockIdx.z == 0;
  const bool act = lane < Hn;
  const int t0 = c*FBL, te = t0 + FBL - 1;

  float pt[Hn];
#pragma unroll
  for (int i = 0; i < Hn; ++i)
    pt[i] = act ? (fwd ? ws[OFF_PT + i*Hn + lane] : ws[OFF_PT + lane*Hn + i]) : 0.f;

  int row_lo, nrows, sA, sZ;
  bool exact;
  if (fwd){
    sA = t0 - FBW;
    exact = (sA < 1);
    row_lo = exact ? 0 : sA;
    if (exact) sA = 1;
    sZ = te;
    nrows = te - row_lo + 1;
  } else {
    int th = te + 1 + FBW;
    exact = (th > Tn - 2);
    sA = exact ? Tn - 2 : th - 1;
    sZ = t0;
    row_lo = t0;
    nrows = sA - t0 + 1;
  }

  // stage exp(lep) = exp(sum of 4 partials) from [m][192] layout
  {
    const float* src = ws + OFF_LEPP + ((size_t)b*Tn + row_lo)*Gn;
    int n4 = nrows * (Hn/4);
    for (int i = lane; i < n4; i += 64){
      int r = i / (Hn/4), h4 = i - r*(Hn/4);
      const float* p = src + (size_t)r*Gn + h4*4;
      float4 a = *(const float4*)(p);
      float4 b2 = *(const float4*)(p + Hn);
      float4 c2 = *(const float4*)(p + 2*Hn);
      float4 d2 = *(const float4*)(p + 3*Hn);
      float4 e;
      e.x = __expf(a.x + b2.x + c2.x + d2.x);
      e.y = __expf(a.y + b2.y + c2.y + d2.y);
      e.z = __expf(a.z + b2.z + c2.z + d2.z);
      e.w = __expf(a.w + b2.w + c2.w + d2.w);
      ((float4*)ldsE)[i] = e;
    }
  }
  __syncthreads();

  if (fwd){
    const size_t laF = OFF_LA + (size_t)b * Tn * Hn;
    float v;
    if (exact){
      v = act ? __expf(ws[OFF_LP + lane]) * ldsE[lane] : 0.f;   // alpha_0
      if (c == 0 && act) ws[laF + lane] = v;
    } else {
      v = act ? 1.f : 0.f;
    }
    if (act) ring[0][lane] = v;
    __syncthreads();
    int cur = 0;
    for (int t = sA; t <= sZ; ++t){
      float S = waveSum(v);
      const float* rp = ring[cur];
      float s0=0.f,s1=0.f,s2=0.f,s3=0.f;
#pragma unroll
      for (int i = 0; i < Hn; i += 4){
        float4 a = *(const float4*)(rp + i);
        s0 = fmaf(a.x, pt[i+0], s0); s1 = fmaf(a.y, pt[i+1], s1);
        s2 = fmaf(a.z, pt[i+2], s2); s3 = fmaf(a.w, pt[i+3], s3);
      }
      float sd = (s0+s1)+(s2+s3);
      float e = act ? ldsE[(t - row_lo)*Hn + lane] : 0.f;
      float vn = act ? e * sd * (1.f/S) : 0.f;
      cur ^= 1;
      if (act) ring[cur][lane] = vn;
      __syncthreads();
      if (act && t >= t0) ws[laF + (size_t)t*Hn + lane] = vn;
      v = vn;
    }
  } else {
    const size_t lbF = OFF_LB + (size_t)b * Tn * Hn;
    float v = act ? 1.f : 0.f;
    if (exact && c == (Tn/FBL - 1) && act) ws[lbF + (size_t)(Tn-1)*Hn + lane] = 1.f;
    int cur = 0;
    for (int t = sA; t >= sZ; --t){
      float e = act ? ldsE[(t - row_lo)*Hn + lane] : 0.f;
      float wv = e * v;
      if (act) ring[cur][lane] = wv;
      float S = waveSum(wv);
      __syncthreads();
      const float* rp = ring[cur];
      float s0=0.f,s1=0.f,s2=0.f,s3=0.f;
#pragma unroll
      for (int j = 0; j < Hn; j += 4){
        float4 a = *(const float4*)(rp + j);
        s0 = fmaf(a.x, pt[j+0], s0); s1 = fmaf(a.y, pt[j+1], s1);
        s2 = fmaf(a.z, pt[j+2], s2); s3 = fmaf(a.w, pt[j+3], s3);
      }
      float vn = act ? ((s0+s1)+(s2+s3)) * (1.f/S) : 0.f;
      cur ^= 1;
      if (act && t <= te) ws[lbF + (size_t)t*Hn + lane] = vn;
      v = vn;
    }
  }
}

// -------- gamma / xi / masked accumulation (prob domain, no atomics) -----------
// One coalesced partial store per block; sum_kernel reduces. (R9's last-block
// counter pattern = 8192 serialized same-address atomics+fences = 165us. Never
// funnel per-block completion through one address on this chip.)
__global__ __launch_bounds__(256) void gamma_xi_kernel(
    const float* __restrict__ ws_c, float* __restrict__ ws,
    const int* __restrict__ seq_len){
  __shared__ float y_s[Hn], lap_s[Hn];
  __shared__ float red[8];
  const int tid = threadIdx.x;
  const int bid = blockIdx.x;
  const int b = bid >> 9, t = bid & (Tn-1);
  const int len = seq_len[b];
  int tb = t + (Tn - len); if (tb >= Tn) tb -= Tn;
  const size_t bt = (size_t)b*Tn + t;
  float lep = 0.f;
  if (tid < Hn){
    const float* lpp = ws_c + OFF_LEPP + bt*Gn + tid;
    lep = lpp[0] + lpp[Hn] + lpp[2*Hn] + lpp[3*Hn];
    float lb  = ws_c[OFF_LB + ((size_t)b*Tn + tb)*Hn + tid];
    y_s[tid] = __expf(lep) * lb;
    if (t >= 1) lap_s[tid] = ws_c[OFF_LA + (bt-1)*Hn + tid];
  }
  float emis_term = 0.f, prior_term = 0.f;
  if (tid < 64){
    int h = (tid < Hn) ? tid : 0;
    float la  = ws_c[OFF_LA + bt*Hn + h];
    float lb  = ws_c[OFF_LB + ((size_t)b*Tn + tb)*Hn + h];
    float lp  = ws_c[OFF_LP + h];
    float wgt = (tid < Hn) ? la*lb : 0.f;
    float Z = waveSum(wgt);
    float inv = 1.f / Z;
    emis_term  = waveSum(wgt * lep) * inv;
    prior_term = waveSum(wgt * lp) * inv;
  }
  __syncthreads();
  float tran_term = 0.f;
  if (t >= 1){
    float se = 0.f, st = 0.f;
#pragma unroll
    for (int k=0;k<9;++k){
      int e = tid + k*256;
      int i = e / Hn, j = e - i*Hn;
      float e2 = ws_c[OFF_PT + e] * lap_s[i] * y_s[j];
      se += e2;
      st = fmaf(e2, ws_c[OFF_LT + e], st);
    }
    se = waveSum(se);
    st = waveSum(st);
    const int wid = tid >> 6;
    if ((tid & 63) == 0){ red[wid] = se; red[4+wid] = st; }
    __syncthreads();
    if (tid == 0){
      float SE = red[0]+red[1]+red[2]+red[3];
      float ST = red[4]+red[5]+red[6]+red[7];
      tran_term = ST / SE;
    }
  }
  if (tid == 0){
    float tot = 0.f;
    if (t < len)            tot += emis_term;
    if (t == 0)             tot += prior_term;
    if (t >= 1 && t < len)  tot += tran_term;
    ws[OFF_RED + bid] = tot;
  }
}

// ---------------- final reduction: 8192 partials -> scalar ---------------------
__global__ __launch_bounds__(256) void sum_kernel(const float* __restrict__ ws,
                                                  float* __restrict__ out){
  __shared__ float red[4];
  const int tid = threadIdx.x;
  float s = 0.f;
  for (int i = tid; i < Mn; i += 256) s += ws[OFF_RED + i];
  s = waveSum(s);
  if ((tid & 63) == 0) red[tid >> 6] = s;
  __syncthreads();
  if (tid == 0) out[0] = (red[0]+red[1]+red[2]+red[3]) * (1.f / Bn);
}

} // namespace

extern "C" void kernel_launch(void* const* d_in, const int* in_sizes, int n_in,
                              void* d_out, int out_size, void* d_ws, size_t ws_size,
                              hipStream_t stream){
  const float* emb = (const float*)d_in[0];
  const float* obs = (const float*)d_in[1];
  const float* sp  = (const float*)d_in[2];
  const float* ut  = (const float*)d_in[3];
  const float* ue  = (const float*)d_in[4];
  const float* Wm  = (const float*)d_in[5];
  const float* bm  = (const float*)d_in[6];
  const int*   sl  = (const int*)d_in[7];
  float* ws  = (float*)d_ws;
  float* out = (float*)d_out;
  (void)in_sizes; (void)n_in; (void)ws_size; (void)out_size;

  unsigned short* embB = (unsigned short*)(ws + FLOATS_END);
  unsigned short* WB   = embB + (size_t)Mn * Dn;

  const int n4a = Mn*Dn/4, n4b = Nn*Dn/4;
  const int nconv = (n4a + n4b + 255)/256;
  convprep_kernel<<<nconv + 1, 256, 0, stream>>>(emb, embB, n4a, Wm, WB, n4b,
                                                 sp, ut, ue, ws, nconv);
  gemm_lep_kernel<<<dim3(Mn/BM, Nn/BN), 256, 0, stream>>>(embB, WB, bm, obs, ws);
  fb_kernel<<<dim3(Tn/FBL, Bn, 2), 64, 0, stream>>>(ws);
  gamma_xi_kernel<<<Bn*Tn, 256, 0, stream>>>(ws, ws, sl);
  sum_kernel<<<1, 256, 0, stream>>>(ws, out);
}

// Round 8
// 285.779 us; speedup vs baseline: 1.2319x; 1.0207x over previous
//
#include <hip/hip_runtime.h>
#include <math.h>

namespace {

constexpr int Bn = 16, Tn = 512, Dn = 768, Sn = 4, Hn = 48, On = 48;
constexpr int Mn = Bn * Tn;          // 8192 (b,t) rows
constexpr int Gn = Sn * Hn;          // 192 (s,h) groups
constexpr int Nn = Gn * On;          // 9216 flat N (= flat W rows)
constexpr float EMISS_W = 0.5f;

// workspace layout (float offsets), then bf16 regions ~27 MB
constexpr size_t OFF_LP   = 0;
constexpr size_t OFF_LT   = 64;
constexpr size_t OFF_PT   = OFF_LT + Hn*Hn;
constexpr size_t OFF_EM   = OFF_PT + Hn*Hn;
constexpr size_t OFF_LEPP = OFF_EM + (size_t)Sn*Hn*On;   // [m][g] g = s*48+h (log partials)
constexpr size_t OFF_LA   = OFF_LEPP + (size_t)Mn*Gn;    // alpha probs (per-t scale)
constexpr size_t OFF_LB   = OFF_LA + (size_t)Mn*Hn;      // beta probs (per-t scale)
constexpr size_t OFF_RED  = OFF_LB + (size_t)Mn*Hn;      // per-(b,t) partials [8192]
constexpr size_t FLOATS_END = OFF_RED + (size_t)Mn;

typedef __attribute__((ext_vector_type(8))) short short8;
typedef __attribute__((ext_vector_type(4))) float f32x4;

__device__ inline float waveSum(float v){
#pragma unroll
  for (int o = 32; o; o >>= 1) v += __shfl_xor(v, o);
  return v;
}

__device__ inline unsigned short f2bf(float f){
  unsigned int u = __float_as_uint(f);
  u += 0x7FFFu + ((u >> 16) & 1u);   // round-to-nearest-even
  return (unsigned short)(u >> 16);
}

__device__ inline void gload_lds16(const void* g, void* l){
  __builtin_amdgcn_global_load_lds(
      (const __attribute__((address_space(1))) void*)g,
      (__attribute__((address_space(3))) void*)l, 16, 0, 0);
}

// -------- conversion (all blocks but last) + param preprocessing (last block) --
__global__ void convprep_kernel(const float* __restrict__ srcA, unsigned short* __restrict__ dstA,
                                int n4a,
                                const float* __restrict__ srcB, unsigned short* __restrict__ dstB,
                                int n4b,
                                const float* __restrict__ sp, const float* __restrict__ ut,
                                const float* __restrict__ ue, float* __restrict__ ws,
                                int nconv){
  const int tid = threadIdx.x;
  if ((int)blockIdx.x == nconv){
    // ---- prep ----
    float m = -INFINITY;
    for (int h = 0; h < Hn; ++h) m = fmaxf(m, sp[h]);
    float s = 0.f;
    for (int h = 0; h < Hn; ++h) s += __expf(sp[h] - m);
    float lse = m + __logf(s);
    if (tid < Hn) ws[OFF_LP + tid] = sp[tid] - lse;
    if (tid < Hn){
      const float* row = ut + tid * Hn;
      float mm = -INFINITY;
      for (int j = 0; j < Hn; ++j) mm = fmaxf(mm, row[j]);
      float ss = 0.f;
      for (int j = 0; j < Hn; ++j) ss += __expf(row[j] - mm);
      float l = mm + __logf(ss);
      for (int j = 0; j < Hn; ++j){
        float v = row[j] - l;
        ws[OFF_LT + tid*Hn + j] = v;
        ws[OFF_PT + tid*Hn + j] = __expf(v);
      }
    }
    for (int r = tid; r < Sn*Hn; r += blockDim.x){
      const float* row = ue + (size_t)r * On;
      float mm = -INFINITY;
      for (int o = 0; o < On; ++o) mm = fmaxf(mm, row[o]);
      float ss = 0.f;
      for (int o = 0; o < On; ++o) ss += __expf(row[o] - mm);
      float inv = 1.f/ss;
      for (int o = 0; o < On; ++o) ws[OFF_EM + (size_t)r*On + o] = __expf(row[o]-mm)*inv;
    }
    return;
  }
  // ---- conv ----
  int i = blockIdx.x * blockDim.x + tid;
  const float* s2; unsigned short* d; int k;
  if (i < n4a){ s2 = srcA; d = dstA; k = i; }
  else { k = i - n4a; if (k >= n4b) return; s2 = srcB; d = dstB; }
  float4 v = ((const float4*)s2)[k];
  ushort4 r;
  r.x = f2bf(v.x); r.y = f2bf(v.y); r.z = f2bf(v.z); r.w = f2bf(v.w);
  ((ushort4*)d)[k] = r;
}

// ---------------- bf16 MFMA GEMM + fused softmax/mix/obs-dot epilogue ----------
// R17 = R14 (129us verified) minus the serializer. R16's BK=32 layout had
// 4-way bank conflicts (64B rows = 4 chunk slots; conflicts 4.7M->16.5M) ->
// reverted to BK=64/128B rows. R14's residual: LDS and MFMA windows fully
// serialized per CU (4300cy/tile vs 2700 modeled). Cause hypothesis (m190):
// setprio(1) around MFMA lets the MFMA-ing wave win ALL issue arbitration,
// blocking the other wave's ds_read issue -> windows alternate globally.
// Fix: (1) remove setprio entirely; (2) cluster-interleave reads and MFMAs
// (read c1 -> stages -> read c2 -> MFMA c1 -> read c3 -> MFMA c2 -> read c4
// -> MFMA c3 -> MFMA c4) so each wave has MFMA work while its later reads
// are serviced. One vmcnt(0)+barrier gate per tile (as R14). 128x192 tile,
// 4 waves (2x2), BK=64, LDS 81920 (2 blocks/CU), slab swizzle verified.
constexpr int BM = 128, BN = 192, BK = 64;
constexpr int NKT = Dn / BK;         // 12 K-tiles
// LDS byte map: A[2] @ 0 (2x16384), B[2] @ 32768 (2x24576), total 81920.

__global__ __launch_bounds__(256, 2) void gemm_lep_kernel(
    const unsigned short* __restrict__ embB, const unsigned short* __restrict__ WB,
    const float* __restrict__ bm, const float* __restrict__ obs,
    float* __restrict__ ws){
  __shared__ __align__(16) char smem[81920];   // staging; aliased by C-park+bias
  const int tid = threadIdx.x, lane = tid & 63, w = tid >> 6;   // w 0..3
  // XCD slab swizzle: 3072 blocks. XCD x owns m-quarter (x&3) x N-half (x>>2);
  // inner loop over m (16 m-tiles, A slab 3.1MB L2-resident), outer over n.
  const int bid = blockIdx.y * (Mn/BM) + blockIdx.x;
  const int xcd = bid & 7, j_loc = bid >> 3;     // j_loc in [0,384)
  const int xm = xcd & 3, xn = xcd >> 2;
  const int mloc = j_loc & 15, nloc = j_loc >> 4; // 16 m-tiles, 24 n-panels
  const int m0 = (xm*16 + mloc) * BM;             // m-tile 0..63
  const int by = xn*24 + nloc;                    // N-panel 0..47
  const int N0 = by * BN;
  const int wm = w & 1, wn = w >> 1;           // 2 x 2 wave grid
  const int lm = lane & 15, q = lane >> 4;
  const int key = lm & 7;
  const int srow = lane >> 3, spc = lane & 7;
  const int aoff0 = (q ^ key) << 4;            // kk=0 chunk byte offset
  const int aoff1 = ((4 + q) ^ key) << 4;      // kk=1

  f32x4 acc[4][6];
#pragma unroll
  for (int i = 0; i < 4; ++i)
#pragma unroll
    for (int j = 0; j < 6; ++j) acc[i][j] = (f32x4){0.f,0.f,0.f,0.f};

  auto stageA = [&](int kt, int i){            // i = 0..3 -> 128 rows
    const int idx = w*4 + i;                   // 0..15
    const int row = idx*8 + srow;
    const int lc  = spc ^ (row & 7);
    gload_lds16(embB + (size_t)(m0+row)*Dn + kt*BK + lc*8,
                smem + (kt & 1)*16384 + idx*1024);
  };
  auto stageB = [&](int kt, int i){            // i = 0..5 -> 192 rows
    const int idx = w*6 + i;                   // 0..23
    const int row = idx*8 + srow;
    const int lc  = spc ^ (row & 7);
    gload_lds16(WB + (size_t)(N0+row)*Dn + kt*BK + lc*8,
                smem + 32768 + (kt & 1)*24576 + idx*1024);
  };

  // prologue: stage K-tile 0 (10 loads); the in-loop gate handles the wait
#pragma unroll
  for (int i = 0; i < 4; ++i) stageA(0, i);
#pragma unroll
  for (int i = 0; i < 6; ++i) stageB(0, i);

  for (int kt = 0; kt < NKT; ++kt){
    const char* Ab = smem + (kt & 1)*16384;
    const char* Bb = smem + 32768 + (kt & 1)*24576;
    const int pf = kt + 1;

    // ---- single gate per tile: own stages landed, all waves past prev tile
    asm volatile("s_waitcnt vmcnt(0)" ::: "memory");
    asm volatile("s_barrier" ::: "memory");

    short8 a0[4], a1[4], b0[3], b1[3], b2[3], b3[3];
    // cluster-1 operands (kk0: B j0-2, A)
#pragma unroll
    for (int j = 0; j < 3; ++j)
      b0[j] = *(const short8*)(Bb + (wn*96 + j*16 + lm)*128 + aoff0);
#pragma unroll
    for (int i = 0; i < 4; ++i)
      a0[i] = *(const short8*)(Ab + (wm*64 + i*16 + lm)*128 + aoff0);
    // issue next-tile stages early (max latency cover; opposite buffer)
    if (pf < NKT){
#pragma unroll
      for (int i = 0; i < 4; ++i) stageA(pf, i);
#pragma unroll
      for (int i = 0; i < 6; ++i) stageB(pf, i);
    }
    // cluster-2 extra reads (kk0: B j3-5)
#pragma unroll
    for (int j = 0; j < 3; ++j)
      b1[j] = *(const short8*)(Bb + (wn*96 + (3+j)*16 + lm)*128 + aoff0);
    // MFMA c1 (overlaps c2/c3 read service)
#pragma unroll
    for (int i = 0; i < 4; ++i)
#pragma unroll
      for (int j = 0; j < 3; ++j)
        acc[i][j] = __builtin_amdgcn_mfma_f32_16x16x32_bf16(a0[i], b0[j], acc[i][j], 0, 0, 0);
    // cluster-3 reads (kk1: A, B j0-2)
#pragma unroll
    for (int i = 0; i < 4; ++i)
      a1[i] = *(const short8*)(Ab + (wm*64 + i*16 + lm)*128 + aoff1);
#pragma unroll
    for (int j = 0; j < 3; ++j)
      b2[j] = *(const short8*)(Bb + (wn*96 + j*16 + lm)*128 + aoff1);
    // MFMA c2
#pragma unroll
    for (int i = 0; i < 4; ++i)
#pragma unroll
      for (int j = 0; j < 3; ++j)
        acc[i][3+j] = __builtin_amdgcn_mfma_f32_16x16x32_bf16(a0[i], b1[j], acc[i][3+j], 0, 0, 0);
    // cluster-4 reads (kk1: B j3-5)
#pragma unroll
    for (int j = 0; j < 3; ++j)
      b3[j] = *(const short8*)(Bb + (wn*96 + (3+j)*16 + lm)*128 + aoff1);
    // MFMA c3
#pragma unroll
    for (int i = 0; i < 4; ++i)
#pragma unroll
      for (int j = 0; j < 3; ++j)
        acc[i][j] = __builtin_amdgcn_mfma_f32_16x16x32_bf16(a1[i], b2[j], acc[i][j], 0, 0, 0);
    // MFMA c4
#pragma unroll
    for (int i = 0; i < 4; ++i)
#pragma unroll
      for (int j = 0; j < 3; ++j)
        acc[i][3+j] = __builtin_amdgcn_mfma_f32_16x16x32_bf16(a1[i], b3[j], acc[i][3+j], 0, 0, 0);
  }

  // ---- epilogue: park C (64 rows x stride 193) + bias/em tables over dead
  //      staging; fused softmax / mix / obs-dot / log. 2 halves of 64 rows;
  //      each half parked by the 2 waves owning it, computed by all 256
  //      threads (64 rows x 4 groups).
  __syncthreads();   // all waves done reading smem before C-park overwrites
  float* Cp  = (float*)smem;
  float* ext = (float*)(smem + 49408);   // bias [0..191], em [192..383]
  if (tid < 192){
    ext[tid]       = bm[N0 + tid];
    ext[192 + tid] = ws[OFF_EM + N0 + tid];
  }
#pragma unroll
  for (int h = 0; h < 2; ++h){
    if (h) __syncthreads();
    if (wm == h){
#pragma unroll
      for (int i = 0; i < 4; ++i)
#pragma unroll
        for (int j = 0; j < 6; ++j){
          const int col = wn*96 + j*16 + lm;
#pragma unroll
          for (int r = 0; r < 4; ++r){
            const int rowl = i*16 + q*4 + r;
            Cp[rowl*193 + col] = acc[i][j][r];
          }
        }
    }
    __syncthreads();
    {
      const int rowl = tid >> 2, grp = tid & 3;
      const int m = m0 + h*64 + rowl;
      const int g = by*4 + grp;
      const int s2 = g / Hn;                   // constant per block
      const float* crow = Cp + rowl*193 + grp*48;
      const float* ob   = obs + ((size_t)m*Sn + s2)*On;
      const float* bi   = ext + grp*48;
      const float* em   = ext + 192 + grp*48;
      float Z = 0.f, pd = 0.f, eo = 0.f;
#pragma unroll
      for (int o = 0; o < On; ++o){
        float e = __expf(crow[o] + bi[o]);
        float obv = ob[o];
        Z += e;
        pd = fmaf(e, obv, pd);
        eo = fmaf(em[o], obv, eo);
      }
      ws[OFF_LEPP + (size_t)m*Gn + g] = __logf((1.f-EMISS_W)*eo + EMISS_W*(pd/Z));
    }
  }
}

// ---------------- forward/backward recursions: chunked with warm-up ----------
// Serial depth 40 (FBW warm-up + FBL chunk). Stages exp(sum of 4 lep
// partials) straight from OFF_LEPP (lep_reduce kernel deleted).
constexpr int FBW = 24;   // warm-up steps
constexpr int FBL = 16;   // chunk length

__global__ __launch_bounds__(64) void fb_kernel(float* __restrict__ ws){
  __shared__ __align__(16) float ldsE[(FBW+FBL)*48];   // exp(lep) window
  __shared__ __align__(16) float ring[2][64];
  const int lane = threadIdx.x;
  const int c    = blockIdx.x;
  const int b    = blockIdx.y;
  const bool fwd = blockIdx.z == 0;
  const bool act = lane < Hn;
  const int t0 = c*FBL, te = t0 + FBL - 1;

  float pt[Hn];
#pragma unroll
  for (int i = 0; i < Hn; ++i)
    pt[i] = act ? (fwd ? ws[OFF_PT + i*Hn + lane] : ws[OFF_PT + lane*Hn + i]) : 0.f;

  int row_lo, nrows, sA, sZ;
  bool exact;
  if (fwd){
    sA = t0 - FBW;
    exact = (sA < 1);
    row_lo = exact ? 0 : sA;
    if (exact) sA = 1;
    sZ = te;
    nrows = te - row_lo + 1;
  } else {
    int th = te + 1 + FBW;
    exact = (th > Tn - 2);
    sA = exact ? Tn - 2 : th - 1;
    sZ = t0;
    row_lo = t0;
    nrows = sA - t0 + 1;
  }

  // stage exp(lep) = exp(sum of 4 partials) from [m][192] layout
  {
    const float* src = ws + OFF_LEPP + ((size_t)b*Tn + row_lo)*Gn;
    int n4 = nrows * (Hn/4);
    for (int i = lane; i < n4; i += 64){
      int r = i / (Hn/4), h4 = i - r*(Hn/4);
      const float* p = src + (size_t)r*Gn + h4*4;
      float4 a = *(const float4*)(p);
      float4 b2 = *(const float4*)(p + Hn);
      float4 c2 = *(const float4*)(p + 2*Hn);
      float4 d2 = *(const float4*)(p + 3*Hn);
      float4 e;
      e.x = __expf(a.x + b2.x + c2.x + d2.x);
      e.y = __expf(a.y + b2.y + c2.y + d2.y);
      e.z = __expf(a.z + b2.z + c2.z + d2.z);
      e.w = __expf(a.w + b2.w + c2.w + d2.w);
      ((float4*)ldsE)[i] = e;
    }
  }
  __syncthreads();

  if (fwd){
    const size_t laF = OFF_LA + (size_t)b * Tn * Hn;
    float v;
    if (exact){
      v = act ? __expf(ws[OFF_LP + lane]) * ldsE[lane] : 0.f;   // alpha_0
      if (c == 0 && act) ws[laF + lane] = v;
    } else {
      v = act ? 1.f : 0.f;
    }
    if (act) ring[0][lane] = v;
    __syncthreads();
    int cur = 0;
    for (int t = sA; t <= sZ; ++t){
      float S = waveSum(v);
      const float* rp = ring[cur];
      float s0=0.f,s1=0.f,s2=0.f,s3=0.f;
#pragma unroll
      for (int i = 0; i < Hn; i += 4){
        float4 a = *(const float4*)(rp + i);
        s0 = fmaf(a.x, pt[i+0], s0); s1 = fmaf(a.y, pt[i+1], s1);
        s2 = fmaf(a.z, pt[i+2], s2); s3 = fmaf(a.w, pt[i+3], s3);
      }
      float sd = (s0+s1)+(s2+s3);
      float e = act ? ldsE[(t - row_lo)*Hn + lane] : 0.f;
      float vn = act ? e * sd * (1.f/S) : 0.f;
      cur ^= 1;
      if (act) ring[cur][lane] = vn;
      __syncthreads();
      if (act && t >= t0) ws[laF + (size_t)t*Hn + lane] = vn;
      v = vn;
    }
  } else {
    const size_t lbF = OFF_LB + (size_t)b * Tn * Hn;
    float v = act ? 1.f : 0.f;
    if (exact && c == (Tn/FBL - 1) && act) ws[lbF + (size_t)(Tn-1)*Hn + lane] = 1.f;
    int cur = 0;
    for (int t = sA; t >= sZ; --t){
      float e = act ? ldsE[(t - row_lo)*Hn + lane] : 0.f;
      float wv = e * v;
      if (act) ring[cur][lane] = wv;
      float S = waveSum(wv);
      __syncthreads();
      const float* rp = ring[cur];
      float s0=0.f,s1=0.f,s2=0.f,s3=0.f;
#pragma unroll
      for (int j = 0; j < Hn; j += 4){
        float4 a = *(const float4*)(rp + j);
        s0 = fmaf(a.x, pt[j+0], s0); s1 = fmaf(a.y, pt[j+1], s1);
        s2 = fmaf(a.z, pt[j+2], s2); s3 = fmaf(a.w, pt[j+3], s3);
      }
      float vn = act ? ((s0+s1)+(s2+s3)) * (1.f/S) : 0.f;
      cur ^= 1;
      if (act && t <= te) ws[lbF + (size_t)t*Hn + lane] = vn;
      v = vn;
    }
  }
}

// -------- gamma / xi / masked accumulation (prob domain, no atomics) -----------
// One coalesced partial store per block; sum_kernel reduces. (R9's last-block
// counter pattern = 8192 serialized same-address atomics+fences = 165us. Never
// funnel per-block completion through one address on this chip.)
__global__ __launch_bounds__(256) void gamma_xi_kernel(
    const float* __restrict__ ws_c, float* __restrict__ ws,
    const int* __restrict__ seq_len){
  __shared__ float y_s[Hn], lap_s[Hn];
  __shared__ float red[8];
  const int tid = threadIdx.x;
  const int bid = blockIdx.x;
  const int b = bid >> 9, t = bid & (Tn-1);
  const int len = seq_len[b];
  int tb = t + (Tn - len); if (tb >= Tn) tb -= Tn;
  const size_t bt = (size_t)b*Tn + t;
  float lep = 0.f;
  if (tid < Hn){
    const float* lpp = ws_c + OFF_LEPP + bt*Gn + tid;
    lep = lpp[0] + lpp[Hn] + lpp[2*Hn] + lpp[3*Hn];
    float lb  = ws_c[OFF_LB + ((size_t)b*Tn + tb)*Hn + tid];
    y_s[tid] = __expf(lep) * lb;
    if (t >= 1) lap_s[tid] = ws_c[OFF_LA + (bt-1)*Hn + tid];
  }
  float emis_term = 0.f, prior_term = 0.f;
  if (tid < 64){
    int h = (tid < Hn) ? tid : 0;
    float la  = ws_c[OFF_LA + bt*Hn + h];
    float lb  = ws_c[OFF_LB + ((size_t)b*Tn + tb)*Hn + h];
    float lp  = ws_c[OFF_LP + h];
    float wgt = (tid < Hn) ? la*lb : 0.f;
    float Z = waveSum(wgt);
    float inv = 1.f / Z;
    emis_term  = waveSum(wgt * lep) * inv;
    prior_term = waveSum(wgt * lp) * inv;
  }
  __syncthreads();
  float tran_term = 0.f;
  if (t >= 1){
    float se = 0.f, st = 0.f;
#pragma unroll
    for (int k=0;k<9;++k){
      int e = tid + k*256;
      int i = e / Hn, j = e - i*Hn;
      float e2 = ws_c[OFF_PT + e] * lap_s[i] * y_s[j];
      se += e2;
      st = fmaf(e2, ws_c[OFF_LT + e], st);
    }
    se = waveSum(se);
    st = waveSum(st);
    const int wid = tid >> 6;
    if ((tid & 63) == 0){ red[wid] = se; red[4+wid] = st; }
    __syncthreads();
    if (tid == 0){
      float SE = red[0]+red[1]+red[2]+red[3];
      float ST = red[4]+red[5]+red[6]+red[7];
      tran_term = ST / SE;
    }
  }
  if (tid == 0){
    float tot = 0.f;
    if (t < len)            tot += emis_term;
    if (t == 0)             tot += prior_term;
    if (t >= 1 && t < len)  tot += tran_term;
    ws[OFF_RED + bid] = tot;
  }
}

// ---------------- final reduction: 8192 partials -> scalar ---------------------
__global__ __launch_bounds__(256) void sum_kernel(const float* __restrict__ ws,
                                                  float* __restrict__ out){
  __shared__ float red[4];
  const int tid = threadIdx.x;
  float s = 0.f;
  for (int i = tid; i < Mn; i += 256) s += ws[OFF_RED + i];
  s = waveSum(s);
  if ((tid & 63) == 0) red[tid >> 6] = s;
  __syncthreads();
  if (tid == 0) out[0] = (red[0]+red[1]+red[2]+red[3]) * (1.f / Bn);
}

} // namespace

extern "C" void kernel_launch(void* const* d_in, const int* in_sizes, int n_in,
                              void* d_out, int out_size, void* d_ws, size_t ws_size,
                              hipStream_t stream){
  const float* emb = (const float*)d_in[0];
  const float* obs = (const float*)d_in[1];
  const float* sp  = (const float*)d_in[2];
  const float* ut  = (const float*)d_in[3];
  const float* ue  = (const float*)d_in[4];
  const float* Wm  = (const float*)d_in[5];
  const float* bm  = (const float*)d_in[6];
  const int*   sl  = (const int*)d_in[7];
  float* ws  = (float*)d_ws;
  float* out = (float*)d_out;
  (void)in_sizes; (void)n_in; (void)ws_size; (void)out_size;

  unsigned short* embB = (unsigned short*)(ws + FLOATS_END);
  unsigned short* WB   = embB + (size_t)Mn * Dn;

  const int n4a = Mn*Dn/4, n4b = Nn*Dn/4;
  const int nconv = (n4a + n4b + 255)/256;
  convprep_kernel<<<nconv + 1, 256, 0, stream>>>(emb, embB, n4a, Wm, WB, n4b,
                                                 sp, ut, ue, ws, nconv);
  gemm_lep_kernel<<<dim3(Mn/BM, Nn/BN), 256, 0, stream>>>(embB, WB, bm, obs, ws);
  fb_kernel<<<dim3(Tn/FBL, Bn, 2), 64, 0, stream>>>(ws);
  gamma_xi_kernel<<<Bn*Tn, 256, 0, stream>>>(ws, ws, sl);
  sum_kernel<<<1, 256, 0, stream>>>(ws, out);
}

// Round 9
// 284.813 us; speedup vs baseline: 1.2361x; 1.0034x over previous
//
#include <hip/hip_runtime.h>
#include <math.h>

namespace {

constexpr int Bn = 16, Tn = 512, Dn = 768, Sn = 4, Hn = 48, On = 48;
constexpr int Mn = Bn * Tn;          // 8192 (b,t) rows
constexpr int Gn = Sn * Hn;          // 192 (s,h) groups
constexpr int Nn = Gn * On;          // 9216 flat N (= flat W rows)
constexpr float EMISS_W = 0.5f;

// workspace layout (float offsets), then bf16 regions ~27 MB
constexpr size_t OFF_LP   = 0;
constexpr size_t OFF_LT   = 64;
constexpr size_t OFF_PT   = OFF_LT + Hn*Hn;
constexpr size_t OFF_EM   = OFF_PT + Hn*Hn;
constexpr size_t OFF_LEPP = OFF_EM + (size_t)Sn*Hn*On;   // [m][g] g = s*48+h (log partials)
constexpr size_t OFF_LA   = OFF_LEPP + (size_t)Mn*Gn;    // alpha probs (per-t scale)
constexpr size_t OFF_LB   = OFF_LA + (size_t)Mn*Hn;      // beta probs (per-t scale)
constexpr size_t OFF_RED  = OFF_LB + (size_t)Mn*Hn;      // per-(b,t) partials [8192]
constexpr size_t FLOATS_END = OFF_RED + (size_t)Mn;

typedef __attribute__((ext_vector_type(8))) short short8;
typedef __attribute__((ext_vector_type(4))) float f32x4;

__device__ inline float waveSum(float v){
#pragma unroll
  for (int o = 32; o; o >>= 1) v += __shfl_xor(v, o);
  return v;
}

__device__ inline unsigned short f2bf(float f){
  unsigned int u = __float_as_uint(f);
  u += 0x7FFFu + ((u >> 16) & 1u);   // round-to-nearest-even
  return (unsigned short)(u >> 16);
}

__device__ inline void gload_lds16(const void* g, void* l){
  __builtin_amdgcn_global_load_lds(
      (const __attribute__((address_space(1))) void*)g,
      (__attribute__((address_space(3))) void*)l, 16, 0, 0);
}

// -------- conversion (all blocks but last) + param preprocessing (last block) --
__global__ void convprep_kernel(const float* __restrict__ srcA, unsigned short* __restrict__ dstA,
                                int n4a,
                                const float* __restrict__ srcB, unsigned short* __restrict__ dstB,
                                int n4b,
                                const float* __restrict__ sp, const float* __restrict__ ut,
                                const float* __restrict__ ue, float* __restrict__ ws,
                                int nconv){
  const int tid = threadIdx.x;
  if ((int)blockIdx.x == nconv){
    // ---- prep ----
    float m = -INFINITY;
    for (int h = 0; h < Hn; ++h) m = fmaxf(m, sp[h]);
    float s = 0.f;
    for (int h = 0; h < Hn; ++h) s += __expf(sp[h] - m);
    float lse = m + __logf(s);
    if (tid < Hn) ws[OFF_LP + tid] = sp[tid] - lse;
    if (tid < Hn){
      const float* row = ut + tid * Hn;
      float mm = -INFINITY;
      for (int j = 0; j < Hn; ++j) mm = fmaxf(mm, row[j]);
      float ss = 0.f;
      for (int j = 0; j < Hn; ++j) ss += __expf(row[j] - mm);
      float l = mm + __logf(ss);
      for (int j = 0; j < Hn; ++j){
        float v = row[j] - l;
        ws[OFF_LT + tid*Hn + j] = v;
        ws[OFF_PT + tid*Hn + j] = __expf(v);
      }
    }
    for (int r = tid; r < Sn*Hn; r += blockDim.x){
      const float* row = ue + (size_t)r * On;
      float mm = -INFINITY;
      for (int o = 0; o < On; ++o) mm = fmaxf(mm, row[o]);
      float ss = 0.f;
      for (int o = 0; o < On; ++o) ss += __expf(row[o] - mm);
      float inv = 1.f/ss;
      for (int o = 0; o < On; ++o) ws[OFF_EM + (size_t)r*On + o] = __expf(row[o]-mm)*inv;
    }
    return;
  }
  // ---- conv ----
  int i = blockIdx.x * blockDim.x + tid;
  const float* s2; unsigned short* d; int k;
  if (i < n4a){ s2 = srcA; d = dstA; k = i; }
  else { k = i - n4a; if (k >= n4b) return; s2 = srcB; d = dstB; }
  float4 v = ((const float4*)s2)[k];
  ushort4 r;
  r.x = f2bf(v.x); r.y = f2bf(v.y); r.z = f2bf(v.z); r.w = f2bf(v.w);
  ((ushort4*)d)[k] = r;
}

// ---------------- bf16 MFMA GEMM + fused softmax/mix/obs-dot epilogue ----------
// R18 = R17 + cross-block anti-phase stagger. Cycle model (matches obs ~5%):
// per CU-tile the LDS pipe carries reads 160KB + stage-writes 80KB ~2800cy,
// MFMA pipe 1862cy. The two co-resident blocks execute IN-PHASE (co-dispatch
// starts them together; contention forces are symmetric, preserving phase):
// reads 1930 (MFMA idle) + MFMA 1862 = 4300cy/tile = the ~130us fixed point
// seen across R13/R14/R17 schedules. Anti-phase would bind only on the LDS
// pipe (~3000cy/tile -> ~100us). Fix: per-block startup delay (bid%3)*640cy
// via s_sleep. Mod-3 is pairing-robust: any power-of-2 co-residency stride
// gives different residues mod 3, so the 2 blocks on a CU always differ by
// 640-1280cy (~half the steady-state period). Everything else == R17:
// 128x192 tile, 4 waves, BK=64, 1 gate/tile, no setprio, LDS 81920
// (2 blocks/CU), XCD slab swizzle (FETCH ~110MB), cluster interleave.
constexpr int BM = 128, BN = 192, BK = 64;
constexpr int NKT = Dn / BK;         // 12 K-tiles
// LDS byte map: A[2] @ 0 (2x16384), B[2] @ 32768 (2x24576), total 81920.

__global__ __launch_bounds__(256, 2) void gemm_lep_kernel(
    const unsigned short* __restrict__ embB, const unsigned short* __restrict__ WB,
    const float* __restrict__ bm, const float* __restrict__ obs,
    float* __restrict__ ws){
  __shared__ __align__(16) char smem[81920];   // staging; aliased by C-park+bias
  const int tid = threadIdx.x, lane = tid & 63, w = tid >> 6;   // w 0..3
  // XCD slab swizzle: 3072 blocks. XCD x owns m-quarter (x&3) x N-half (x>>2);
  // inner loop over m (16 m-tiles, A slab 3.1MB L2-resident), outer over n.
  const int bid = blockIdx.y * (Mn/BM) + blockIdx.x;
  const int xcd = bid & 7, j_loc = bid >> 3;     // j_loc in [0,384)
  const int xm = xcd & 3, xn = xcd >> 2;
  const int mloc = j_loc & 15, nloc = j_loc >> 4; // 16 m-tiles, 24 n-panels
  const int m0 = (xm*16 + mloc) * BM;             // m-tile 0..63
  const int by = xn*24 + nloc;                    // N-panel 0..47
  const int N0 = by * BN;
  const int wm = w & 1, wn = w >> 1;           // 2 x 2 wave grid
  const int lm = lane & 15, q = lane >> 4;
  const int key = lm & 7;
  const int srow = lane >> 3, spc = lane & 7;
  const int aoff0 = (q ^ key) << 4;            // kk=0 chunk byte offset
  const int aoff1 = ((4 + q) ^ key) << 4;      // kk=1

  f32x4 acc[4][6];
#pragma unroll
  for (int i = 0; i < 4; ++i)
#pragma unroll
    for (int j = 0; j < 6; ++j) acc[i][j] = (f32x4){0.f,0.f,0.f,0.f};

  auto stageA = [&](int kt, int i){            // i = 0..3 -> 128 rows
    const int idx = w*4 + i;                   // 0..15
    const int row = idx*8 + srow;
    const int lc  = spc ^ (row & 7);
    gload_lds16(embB + (size_t)(m0+row)*Dn + kt*BK + lc*8,
                smem + (kt & 1)*16384 + idx*1024);
  };
  auto stageB = [&](int kt, int i){            // i = 0..5 -> 192 rows
    const int idx = w*6 + i;                   // 0..23
    const int row = idx*8 + srow;
    const int lc  = spc ^ (row & 7);
    gload_lds16(WB + (size_t)(N0+row)*Dn + kt*BK + lc*8,
                smem + 32768 + (kt & 1)*24576 + idx*1024);
  };

  // prologue: stage K-tile 0 (10 loads); the in-loop gate handles the wait
#pragma unroll
  for (int i = 0; i < 4; ++i) stageA(0, i);
#pragma unroll
  for (int i = 0; i < 6; ++i) stageB(0, i);

  // ---- anti-phase stagger: (bid%3) x ~640cy startup delay ----
  {
    const int ph = bid % 3;
    if (ph > 0) asm volatile("s_sleep 10" ::: "memory");
    if (ph > 1) asm volatile("s_sleep 10" ::: "memory");
  }

  for (int kt = 0; kt < NKT; ++kt){
    const char* Ab = smem + (kt & 1)*16384;
    const char* Bb = smem + 32768 + (kt & 1)*24576;
    const int pf = kt + 1;

    // ---- single gate per tile: own stages landed, all waves past prev tile
    asm volatile("s_waitcnt vmcnt(0)" ::: "memory");
    asm volatile("s_barrier" ::: "memory");

    short8 a0[4], a1[4], b0[3], b1[3], b2[3], b3[3];
    // cluster-1 operands (kk0: B j0-2, A)
#pragma unroll
    for (int j = 0; j < 3; ++j)
      b0[j] = *(const short8*)(Bb + (wn*96 + j*16 + lm)*128 + aoff0);
#pragma unroll
    for (int i = 0; i < 4; ++i)
      a0[i] = *(const short8*)(Ab + (wm*64 + i*16 + lm)*128 + aoff0);
    // issue next-tile stages early (max latency cover; opposite buffer)
    if (pf < NKT){
#pragma unroll
      for (int i = 0; i < 4; ++i) stageA(pf, i);
#pragma unroll
      for (int i = 0; i < 6; ++i) stageB(pf, i);
    }
    // cluster-2 extra reads (kk0: B j3-5)
#pragma unroll
    for (int j = 0; j < 3; ++j)
      b1[j] = *(const short8*)(Bb + (wn*96 + (3+j)*16 + lm)*128 + aoff0);
    // MFMA c1 (overlaps c2/c3 read service)
#pragma unroll
    for (int i = 0; i < 4; ++i)
#pragma unroll
      for (int j = 0; j < 3; ++j)
        acc[i][j] = __builtin_amdgcn_mfma_f32_16x16x32_bf16(a0[i], b0[j], acc[i][j], 0, 0, 0);
    // cluster-3 reads (kk1: A, B j0-2)
#pragma unroll
    for (int i = 0; i < 4; ++i)
      a1[i] = *(const short8*)(Ab + (wm*64 + i*16 + lm)*128 + aoff1);
#pragma unroll
    for (int j = 0; j < 3; ++j)
      b2[j] = *(const short8*)(Bb + (wn*96 + j*16 + lm)*128 + aoff1);
    // MFMA c2
#pragma unroll
    for (int i = 0; i < 4; ++i)
#pragma unroll
      for (int j = 0; j < 3; ++j)
        acc[i][3+j] = __builtin_amdgcn_mfma_f32_16x16x32_bf16(a0[i], b1[j], acc[i][3+j], 0, 0, 0);
    // cluster-4 reads (kk1: B j3-5)
#pragma unroll
    for (int j = 0; j < 3; ++j)
      b3[j] = *(const short8*)(Bb + (wn*96 + (3+j)*16 + lm)*128 + aoff1);
    // MFMA c3
#pragma unroll
    for (int i = 0; i < 4; ++i)
#pragma unroll
      for (int j = 0; j < 3; ++j)
        acc[i][j] = __builtin_amdgcn_mfma_f32_16x16x32_bf16(a1[i], b2[j], acc[i][j], 0, 0, 0);
    // MFMA c4
#pragma unroll
    for (int i = 0; i < 4; ++i)
#pragma unroll
      for (int j = 0; j < 3; ++j)
        acc[i][3+j] = __builtin_amdgcn_mfma_f32_16x16x32_bf16(a1[i], b3[j], acc[i][3+j], 0, 0, 0);
  }

  // ---- epilogue: park C (64 rows x stride 193) + bias/em tables over dead
  //      staging; fused softmax / mix / obs-dot / log. 2 halves of 64 rows;
  //      each half parked by the 2 waves owning it, computed by all 256
  //      threads (64 rows x 4 groups).
  __syncthreads();   // all waves done reading smem before C-park overwrites
  float* Cp  = (float*)smem;
  float* ext = (float*)(smem + 49408);   // bias [0..191], em [192..383]
  if (tid < 192){
    ext[tid]       = bm[N0 + tid];
    ext[192 + tid] = ws[OFF_EM + N0 + tid];
  }
#pragma unroll
  for (int h = 0; h < 2; ++h){
    if (h) __syncthreads();
    if (wm == h){
#pragma unroll
      for (int i = 0; i < 4; ++i)
#pragma unroll
        for (int j = 0; j < 6; ++j){
          const int col = wn*96 + j*16 + lm;
#pragma unroll
          for (int r = 0; r < 4; ++r){
            const int rowl = i*16 + q*4 + r;
            Cp[rowl*193 + col] = acc[i][j][r];
          }
        }
    }
    __syncthreads();
    {
      const int rowl = tid >> 2, grp = tid & 3;
      const int m = m0 + h*64 + rowl;
      const int g = by*4 + grp;
      const int s2 = g / Hn;                   // constant per block
      const float* crow = Cp + rowl*193 + grp*48;
      const float* ob   = obs + ((size_t)m*Sn + s2)*On;
      const float* bi   = ext + grp*48;
      const float* em   = ext + 192 + grp*48;
      float Z = 0.f, pd = 0.f, eo = 0.f;
#pragma unroll
      for (int o = 0; o < On; ++o){
        float e = __expf(crow[o] + bi[o]);
        float obv = ob[o];
        Z += e;
        pd = fmaf(e, obv, pd);
        eo = fmaf(em[o], obv, eo);
      }
      ws[OFF_LEPP + (size_t)m*Gn + g] = __logf((1.f-EMISS_W)*eo + EMISS_W*(pd/Z));
    }
  }
}

// ---------------- forward/backward recursions: chunked with warm-up ----------
// Serial depth 40 (FBW warm-up + FBL chunk). Stages exp(sum of 4 lep
// partials) straight from OFF_LEPP (lep_reduce kernel deleted).
constexpr int FBW = 24;   // warm-up steps
constexpr int FBL = 16;   // chunk length

__global__ __launch_bounds__(64) void fb_kernel(float* __restrict__ ws){
  __shared__ __align__(16) float ldsE[(FBW+FBL)*48];   // exp(lep) window
  __shared__ __align__(16) float ring[2][64];
  const int lane = threadIdx.x;
  const int c    = blockIdx.x;
  const int b    = blockIdx.y;
  const bool fwd = blockIdx.z == 0;
  const bool act = lane < Hn;
  const int t0 = c*FBL, te = t0 + FBL - 1;

  float pt[Hn];
#pragma unroll
  for (int i = 0; i < Hn; ++i)
    pt[i] = act ? (fwd ? ws[OFF_PT + i*Hn + lane] : ws[OFF_PT + lane*Hn + i]) : 0.f;

  int row_lo, nrows, sA, sZ;
  bool exact;
  if (fwd){
    sA = t0 - FBW;
    exact = (sA < 1);
    row_lo = exact ? 0 : sA;
    if (exact) sA = 1;
    sZ = te;
    nrows = te - row_lo + 1;
  } else {
    int th = te + 1 + FBW;
    exact = (th > Tn - 2);
    sA = exact ? Tn - 2 : th - 1;
    sZ = t0;
    row_lo = t0;
    nrows = sA - t0 + 1;
  }

  // stage exp(lep) = exp(sum of 4 partials) from [m][192] layout
  {
    const float* src = ws + OFF_LEPP + ((size_t)b*Tn + row_lo)*Gn;
    int n4 = nrows * (Hn/4);
    for (int i = lane; i < n4; i += 64){
      int r = i / (Hn/4), h4 = i - r*(Hn/4);
      const float* p = src + (size_t)r*Gn + h4*4;
      float4 a = *(const float4*)(p);
      float4 b2 = *(const float4*)(p + Hn);
      float4 c2 = *(const float4*)(p + 2*Hn);
      float4 d2 = *(const float4*)(p + 3*Hn);
      float4 e;
      e.x = __expf(a.x + b2.x + c2.x + d2.x);
      e.y = __expf(a.y + b2.y + c2.y + d2.y);
      e.z = __expf(a.z + b2.z + c2.z + d2.z);
      e.w = __expf(a.w + b2.w + c2.w + d2.w);
      ((float4*)ldsE)[i] = e;
    }
  }
  __syncthreads();

  if (fwd){
    const size_t laF = OFF_LA + (size_t)b * Tn * Hn;
    float v;
    if (exact){
      v = act ? __expf(ws[OFF_LP + lane]) * ldsE[lane] : 0.f;   // alpha_0
      if (c == 0 && act) ws[laF + lane] = v;
    } else {
      v = act ? 1.f : 0.f;
    }
    if (act) ring[0][lane] = v;
    __syncthreads();
    int cur = 0;
    for (int t = sA; t <= sZ; ++t){
      float S = waveSum(v);
      const float* rp = ring[cur];
      float s0=0.f,s1=0.f,s2=0.f,s3=0.f;
#pragma unroll
      for (int i = 0; i < Hn; i += 4){
        float4 a = *(const float4*)(rp + i);
        s0 = fmaf(a.x, pt[i+0], s0); s1 = fmaf(a.y, pt[i+1], s1);
        s2 = fmaf(a.z, pt[i+2], s2); s3 = fmaf(a.w, pt[i+3], s3);
      }
      float sd = (s0+s1)+(s2+s3);
      float e = act ? ldsE[(t - row_lo)*Hn + lane] : 0.f;
      float vn = act ? e * sd * (1.f/S) : 0.f;
      cur ^= 1;
      if (act) ring[cur][lane] = vn;
      __syncthreads();
      if (act && t >= t0) ws[laF + (size_t)t*Hn + lane] = vn;
      v = vn;
    }
  } else {
    const size_t lbF = OFF_LB + (size_t)b * Tn * Hn;
    float v = act ? 1.f : 0.f;
    if (exact && c == (Tn/FBL - 1) && act) ws[lbF + (size_t)(Tn-1)*Hn + lane] = 1.f;
    int cur = 0;
    for (int t = sA; t >= sZ; --t){
      float e = act ? ldsE[(t - row_lo)*Hn + lane] : 0.f;
      float wv = e * v;
      if (act) ring[cur][lane] = wv;
      float S = waveSum(wv);
      __syncthreads();
      const float* rp = ring[cur];
      float s0=0.f,s1=0.f,s2=0.f,s3=0.f;
#pragma unroll
      for (int j = 0; j < Hn; j += 4){
        float4 a = *(const float4*)(rp + j);
        s0 = fmaf(a.x, pt[j+0], s0); s1 = fmaf(a.y, pt[j+1], s1);
        s2 = fmaf(a.z, pt[j+2], s2); s3 = fmaf(a.w, pt[j+3], s3);
      }
      float vn = act ? ((s0+s1)+(s2+s3)) * (1.f/S) : 0.f;
      cur ^= 1;
      if (act && t <= te) ws[lbF + (size_t)t*Hn + lane] = vn;
      v = vn;
    }
  }
}

// -------- gamma / xi / masked accumulation (prob domain, no atomics) -----------
// One coalesced partial store per block; sum_kernel reduces. (R9's last-block
// counter pattern = 8192 serialized same-address atomics+fences = 165us. Never
// funnel per-block completion through one address on this chip.)
__global__ __launch_bounds__(256) void gamma_xi_kernel(
    const float* __restrict__ ws_c, float* __restrict__ ws,
    const int* __restrict__ seq_len){
  __shared__ float y_s[Hn], lap_s[Hn];
  __shared__ float red[8];
  const int tid = threadIdx.x;
  const int bid = blockIdx.x;
  const int b = bid >> 9, t = bid & (Tn-1);
  const int len = seq_len[b];
  int tb = t + (Tn - len); if (tb >= Tn) tb -= Tn;
  const size_t bt = (size_t)b*Tn + t;
  float lep = 0.f;
  if (tid < Hn){
    const float* lpp = ws_c + OFF_LEPP + bt*Gn + tid;
    lep = lpp[0] + lpp[Hn] + lpp[2*Hn] + lpp[3*Hn];
    float lb  = ws_c[OFF_LB + ((size_t)b*Tn + tb)*Hn + tid];
    y_s[tid] = __expf(lep) * lb;
    if (t >= 1) lap_s[tid] = ws_c[OFF_LA + (bt-1)*Hn + tid];
  }
  float emis_term = 0.f, prior_term = 0.f;
  if (tid < 64){
    int h = (tid < Hn) ? tid : 0;
    float la  = ws_c[OFF_LA + bt*Hn + h];
    float lb  = ws_c[OFF_LB + ((size_t)b*Tn + tb)*Hn + h];
    float lp  = ws_c[OFF_LP + h];
    float wgt = (tid < Hn) ? la*lb : 0.f;
    float Z = waveSum(wgt);
    float inv = 1.f / Z;
    emis_term  = waveSum(wgt * lep) * inv;
    prior_term = waveSum(wgt * lp) * inv;
  }
  __syncthreads();
  float tran_term = 0.f;
  if (t >= 1){
    float se = 0.f, st = 0.f;
#pragma unroll
    for (int k=0;k<9;++k){
      int e = tid + k*256;
      int i = e / Hn, j = e - i*Hn;
      float e2 = ws_c[OFF_PT + e] * lap_s[i] * y_s[j];
      se += e2;
      st = fmaf(e2, ws_c[OFF_LT + e], st);
    }
    se = waveSum(se);
    st = waveSum(st);
    const int wid = tid >> 6;
    if ((tid & 63) == 0){ red[wid] = se; red[4+wid] = st; }
    __syncthreads();
    if (tid == 0){
      float SE = red[0]+red[1]+red[2]+red[3];
      float ST = red[4]+red[5]+red[6]+red[7];
      tran_term = ST / SE;
    }
  }
  if (tid == 0){
    float tot = 0.f;
    if (t < len)            tot += emis_term;
    if (t == 0)             tot += prior_term;
    if (t >= 1 && t < len)  tot += tran_term;
    ws[OFF_RED + bid] = tot;
  }
}

// ---------------- final reduction: 8192 partials -> scalar ---------------------
__global__ __launch_bounds__(256) void sum_kernel(const float* __restrict__ ws,
                                                  float* __restrict__ out){
  __shared__ float red[4];
  const int tid = threadIdx.x;
  float s = 0.f;
  for (int i = tid; i < Mn; i += 256) s += ws[OFF_RED + i];
  s = waveSum(s);
  if ((tid & 63) == 0) red[tid >> 6] = s;
  __syncthreads();
  if (tid == 0) out[0] = (red[0]+red[1]+red[2]+red[3]) * (1.f / Bn);
}

} // namespace

extern "C" void kernel_launch(void* const* d_in, const int* in_sizes, int n_in,
                              void* d_out, int out_size, void* d_ws, size_t ws_size,
                              hipStream_t stream){
  const float* emb = (const float*)d_in[0];
  const float* obs = (const float*)d_in[1];
  const float* sp  = (const float*)d_in[2];
  const float* ut  = (const float*)d_in[3];
  const float* ue  = (const float*)d_in[4];
  const float* Wm  = (const float*)d_in[5];
  const float* bm  = (const float*)d_in[6];
  const int*   sl  = (const int*)d_in[7];
  float* ws  = (float*)d_ws;
  float* out = (float*)d_out;
  (void)in_sizes; (void)n_in; (void)ws_size; (void)out_size;

  unsigned short* embB = (unsigned short*)(ws + FLOATS_END);
  unsigned short* WB   = embB + (size_t)Mn * Dn;

  const int n4a = Mn*Dn/4, n4b = Nn*Dn/4;
  const int nconv = (n4a + n4b + 255)/256;
  convprep_kernel<<<nconv + 1, 256, 0, stream>>>(emb, embB, n4a, Wm, WB, n4b,
                                                 sp, ut, ue, ws, nconv);
  gemm_lep_kernel<<<dim3(Mn/BM, Nn/BN), 256, 0, stream>>>(embB, WB, bm, obs, ws);
  fb_kernel<<<dim3(Tn/FBL, Bn, 2), 64, 0, stream>>>(ws);
  gamma_xi_kernel<<<Bn*Tn, 256, 0, stream>>>(ws, ws, sl);
  sum_kernel<<<1, 256, 0, stream>>>(ws, out);
}

// Round 10
// 278.478 us; speedup vs baseline: 1.2642x; 1.0227x over previous
//
#include <hip/hip_runtime.h>
#include <math.h>

namespace {

constexpr int Bn = 16, Tn = 512, Dn = 768, Sn = 4, Hn = 48, On = 48;
constexpr int Mn = Bn * Tn;          // 8192 (b,t) rows
constexpr int Gn = Sn * Hn;          // 192 (s,h) groups
constexpr int Nn = Gn * On;          // 9216 flat N (= flat W rows)
constexpr float EMISS_W = 0.5f;

// workspace layout (float offsets), then bf16 regions ~27 MB
constexpr size_t OFF_LP   = 0;
constexpr size_t OFF_LT   = 64;
constexpr size_t OFF_PT   = OFF_LT + Hn*Hn;
constexpr size_t OFF_EM   = OFF_PT + Hn*Hn;
constexpr size_t OFF_LEPP = OFF_EM + (size_t)Sn*Hn*On;   // [m][g] g = s*48+h (log partials)
constexpr size_t OFF_LA   = OFF_LEPP + (size_t)Mn*Gn;    // alpha probs (per-t scale)
constexpr size_t OFF_LB   = OFF_LA + (size_t)Mn*Hn;      // beta probs (per-t scale)
constexpr size_t OFF_RED  = OFF_LB + (size_t)Mn*Hn;      // per-(b,t) partials [8192]
constexpr size_t FLOATS_END = OFF_RED + (size_t)Mn;

typedef __attribute__((ext_vector_type(8))) short short8;
typedef __attribute__((ext_vector_type(4))) float f32x4;

__device__ inline float waveSum(float v){
#pragma unroll
  for (int o = 32; o; o >>= 1) v += __shfl_xor(v, o);
  return v;
}

__device__ inline unsigned short f2bf(float f){
  unsigned int u = __float_as_uint(f);
  u += 0x7FFFu + ((u >> 16) & 1u);   // round-to-nearest-even
  return (unsigned short)(u >> 16);
}

__device__ inline void gload_lds16(const void* g, void* l){
  __builtin_amdgcn_global_load_lds(
      (const __attribute__((address_space(1))) void*)g,
      (__attribute__((address_space(3))) void*)l, 16, 0, 0);
}

// -------- conversion (all blocks but last) + param preprocessing (last block) --
__global__ void convprep_kernel(const float* __restrict__ srcA, unsigned short* __restrict__ dstA,
                                int n4a,
                                const float* __restrict__ srcB, unsigned short* __restrict__ dstB,
                                int n4b,
                                const float* __restrict__ sp, const float* __restrict__ ut,
                                const float* __restrict__ ue, float* __restrict__ ws,
                                int nconv){
  const int tid = threadIdx.x;
  if ((int)blockIdx.x == nconv){
    // ---- prep ----
    float m = -INFINITY;
    for (int h = 0; h < Hn; ++h) m = fmaxf(m, sp[h]);
    float s = 0.f;
    for (int h = 0; h < Hn; ++h) s += __expf(sp[h] - m);
    float lse = m + __logf(s);
    if (tid < Hn) ws[OFF_LP + tid] = sp[tid] - lse;
    if (tid < Hn){
      const float* row = ut + tid * Hn;
      float mm = -INFINITY;
      for (int j = 0; j < Hn; ++j) mm = fmaxf(mm, row[j]);
      float ss = 0.f;
      for (int j = 0; j < Hn; ++j) ss += __expf(row[j] - mm);
      float l = mm + __logf(ss);
      for (int j = 0; j < Hn; ++j){
        float v = row[j] - l;
        ws[OFF_LT + tid*Hn + j] = v;
        ws[OFF_PT + tid*Hn + j] = __expf(v);
      }
    }
    for (int r = tid; r < Sn*Hn; r += blockDim.x){
      const float* row = ue + (size_t)r * On;
      float mm = -INFINITY;
      for (int o = 0; o < On; ++o) mm = fmaxf(mm, row[o]);
      float ss = 0.f;
      for (int o = 0; o < On; ++o) ss += __expf(row[o] - mm);
      float inv = 1.f/ss;
      for (int o = 0; o < On; ++o) ws[OFF_EM + (size_t)r*On + o] = __expf(row[o]-mm)*inv;
    }
    return;
  }
  // ---- conv ----
  int i = blockIdx.x * blockDim.x + tid;
  const float* s2; unsigned short* d; int k;
  if (i < n4a){ s2 = srcA; d = dstA; k = i; }
  else { k = i - n4a; if (k >= n4b) return; s2 = srcB; d = dstB; }
  float4 v = ((const float4*)s2)[k];
  ushort4 r;
  r.x = f2bf(v.x); r.y = f2bf(v.y); r.z = f2bf(v.z); r.w = f2bf(v.w);
  ((ushort4*)d)[k] = r;
}

// ---------------- bf16 MFMA GEMM + fused softmax/mix/obs-dot epilogue ----------
// R19: the untested matrix cell {fine phases + covered counted vmcnt +
// 2 waves/SIMD + clean layout}. 256x192 tile, 8 waves (2Mx4N, wave 128x48),
// BK=64, double buffer 112KB (1 block/CU). TWO phases per tile with
// B-read-once: P1 = A i0-3 (both kk) + ALL B (6 reads) -> 24 MFMA;
// P2 = A i4-7 (8 reads), reuse B regs -> 24 MFMA. 22 reads/wave/tile
// (vs 28 in R12). Stage regions == phase-read regions: per wave 5
// region-1 loads {A-p1 idx w & 16+w, B x3}, then 2 region-2 {A-p2 idx
// 8+w & 24+w}. Gates COUNTED with >=2-phase (~1300cy) cover: tile gate
// vmcnt(2) (drains r1 of this tile, keeps this tile's A-p2); mid gate
// vmcnt(5) (drains A-p2, keeps next tile's 5 r1 issued in P1). Never
// drains a recent load (m218: counted-vs-drain0 = +38-73% on phased
// structures; overlap needs 2 waves/SIMD for intra-phase pipelining).
// setprio around MFMA (T5 pays on phased+counted, m218b). Slab swizzle
// = R10/R11 numbers (A slab 3.1MB/XCD, FETCH ~110MB verified).
constexpr int BM = 256, BN = 192, BK = 64;
constexpr int NKT = Dn / BK;         // 12 K-tiles
// LDS byte map: A[2] @ 0 (2x32768), B[2] @ 65536 (2x24576), total 114688.

__global__ __launch_bounds__(512, 1) void gemm_lep_kernel(
    const unsigned short* __restrict__ embB, const unsigned short* __restrict__ WB,
    const float* __restrict__ bm, const float* __restrict__ obs,
    float* __restrict__ ws){
  __shared__ __align__(16) char smem[114688];   // staging; aliased by C-park+bias
  const int tid = threadIdx.x, lane = tid & 63, w = tid >> 6;   // w 0..7
  // XCD slab swizzle: 1536 blocks. XCD x owns m-quarter (x&3) x N-half (x>>2);
  // inner loop over m (8 m-tiles of 256 rows = 3.1MB A slab, L2-resident).
  const int bid = blockIdx.y * (Mn/BM) + blockIdx.x;
  const int xcd = bid & 7, j_loc = bid >> 3;     // j_loc in [0,192)
  const int xm = xcd & 3, xn = xcd >> 2;
  const int mloc = j_loc & 7, nloc = j_loc >> 3; // 8 m-tiles, 24 n-panels
  const int m0 = (xm*8 + mloc) * BM;             // m-tile 0..31
  const int by = xn*24 + nloc;                   // N-panel 0..47
  const int N0 = by * BN;
  const int wm = w & 1, wn = w >> 1;           // 2 x 4 wave grid
  const int lm = lane & 15, q = lane >> 4;
  const int key = lm & 7;
  const int srow = lane >> 3, spc = lane & 7;
  const int aoff0 = (q ^ key) << 4;            // kk=0 chunk byte offset
  const int aoff1 = ((4 + q) ^ key) << 4;      // kk=1

  f32x4 acc[8][3];
#pragma unroll
  for (int i = 0; i < 8; ++i)
#pragma unroll
    for (int j = 0; j < 3; ++j) acc[i][j] = (f32x4){0.f,0.f,0.f,0.f};

  // A stages: region-1 (phase-1 rows: 0-63 & 128-191) = idx {w, 16+w};
  //           region-2 (phase-2 rows: 64-127 & 192-255) = idx {8+w, 24+w}.
  auto stageA = [&](int kt, int idx){
    const int row = idx*8 + srow;
    const int lc  = spc ^ (row & 7);
    gload_lds16(embB + (size_t)(m0+row)*Dn + kt*BK + lc*8,
                smem + (kt & 1)*32768 + idx*1024);
  };
  auto stageB = [&](int kt, int i){            // i = 0..2, idx 0..23
    const int idx = w*3 + i;
    const int row = idx*8 + srow;
    const int lc  = spc ^ (row & 7);
    gload_lds16(WB + (size_t)(N0+row)*Dn + kt*BK + lc*8,
                smem + 65536 + (kt & 1)*24576 + idx*1024);
  };

  // prologue: tile 0, region order [5 x r1, 2 x r2]
  stageA(0, w); stageA(0, 16 + w);
  stageB(0, 0); stageB(0, 1); stageB(0, 2);
  stageA(0, 8 + w); stageA(0, 24 + w);

  for (int kt = 0; kt < NKT; ++kt){
    const char* Ab = smem + (kt & 1)*32768;
    const char* Bb = smem + 65536 + (kt & 1)*24576;
    const int pf = kt + 1;
    const bool dopf = pf < NKT;

    // ---- tile gate: drain this tile's 5 region-1 loads (issued >=2 phases
    //      ago); keep its 2 A-p2 loads in flight
    asm volatile("s_waitcnt vmcnt(2)" ::: "memory");
    asm volatile("s_barrier" ::: "memory");

    // ---- P1: reads A i0-3 (both kk) + ALL B (both kk)
    short8 a0[4], a1[4], b0[3], b1[3];
#pragma unroll
    for (int j = 0; j < 3; ++j){
      const char* bp = Bb + (wn*48 + j*16 + lm)*128;
      b0[j] = *(const short8*)(bp + aoff0);
      b1[j] = *(const short8*)(bp + aoff1);
    }
#pragma unroll
    for (int i = 0; i < 4; ++i){
      const char* ap = Ab + (wm*128 + i*16 + lm)*128;
      a0[i] = *(const short8*)(ap + aoff0);
      a1[i] = *(const short8*)(ap + aoff1);
    }
    if (dopf){                                  // 5 region-1 stages for t+1
      stageA(pf, w); stageA(pf, 16 + w);
      stageB(pf, 0); stageB(pf, 1); stageB(pf, 2);
    }
    __builtin_amdgcn_s_setprio(1);
#pragma unroll
    for (int i = 0; i < 4; ++i)
#pragma unroll
      for (int j = 0; j < 3; ++j)
        acc[i][j] = __builtin_amdgcn_mfma_f32_16x16x32_bf16(a0[i], b0[j], acc[i][j], 0, 0, 0);
#pragma unroll
    for (int i = 0; i < 4; ++i)
#pragma unroll
      for (int j = 0; j < 3; ++j)
        acc[i][j] = __builtin_amdgcn_mfma_f32_16x16x32_bf16(a1[i], b1[j], acc[i][j], 0, 0, 0);
    __builtin_amdgcn_s_setprio(0);

    // ---- mid gate: drain this tile's 2 A-p2 loads (issued a full tile ago);
    //      keep t+1's 5 region-1 loads (just issued) in flight
    if (dopf) asm volatile("s_waitcnt vmcnt(5)" ::: "memory");
    else      asm volatile("s_waitcnt vmcnt(0)" ::: "memory");
    asm volatile("s_barrier" ::: "memory");

    // ---- P2: reads A i4-7 (both kk); B fragments reused from registers
    short8 a2[4], a3[4];
#pragma unroll
    for (int i = 0; i < 4; ++i){
      const char* ap = Ab + (wm*128 + 64 + i*16 + lm)*128;
      a2[i] = *(const short8*)(ap + aoff0);
      a3[i] = *(const short8*)(ap + aoff1);
    }
    if (dopf){ stageA(pf, 8 + w); stageA(pf, 24 + w); }  // 2 region-2 stages
    __builtin_amdgcn_s_setprio(1);
#pragma unroll
    for (int i = 0; i < 4; ++i)
#pragma unroll
      for (int j = 0; j < 3; ++j)
        acc[4+i][j] = __builtin_amdgcn_mfma_f32_16x16x32_bf16(a2[i], b0[j], acc[4+i][j], 0, 0, 0);
#pragma unroll
    for (int i = 0; i < 4; ++i)
#pragma unroll
      for (int j = 0; j < 3; ++j)
        acc[4+i][j] = __builtin_amdgcn_mfma_f32_16x16x32_bf16(a3[i], b1[j], acc[4+i][j], 0, 0, 0);
    __builtin_amdgcn_s_setprio(0);
  }

  // ---- epilogue: park C in 2 halves of 128 rows (stride 193) over dead
  //      staging + bias/em tables; fused softmax / mix / obs-dot / log.
  //      512 threads = 128 rows x 4 groups per half.
  __syncthreads();   // all waves done reading smem before C-park overwrites
  float* Cp  = (float*)smem;
  float* ext = (float*)(smem + 98816);   // bias [0..191], em [192..383]
  if (tid < 192){
    ext[tid]       = bm[N0 + tid];
    ext[192 + tid] = ws[OFF_EM + N0 + tid];
  }
#pragma unroll
  for (int h = 0; h < 2; ++h){
    if (h) __syncthreads();
    if (wm == h){
#pragma unroll
      for (int i = 0; i < 8; ++i)
#pragma unroll
        for (int j = 0; j < 3; ++j){
          const int col = wn*48 + j*16 + lm;
#pragma unroll
          for (int r = 0; r < 4; ++r){
            const int rowl = i*16 + q*4 + r;
            Cp[rowl*193 + col] = acc[i][j][r];
          }
        }
    }
    __syncthreads();
    {
      const int rowl = tid >> 2, grp = tid & 3;
      const int m = m0 + h*128 + rowl;
      const int g = by*4 + grp;
      const int s2 = g / Hn;                   // constant per block
      const float* crow = Cp + rowl*193 + grp*48;
      const float* ob   = obs + ((size_t)m*Sn + s2)*On;
      const float* bi   = ext + grp*48;
      const float* em   = ext + 192 + grp*48;
      float Z = 0.f, pd = 0.f, eo = 0.f;
#pragma unroll
      for (int o = 0; o < On; ++o){
        float e = __expf(crow[o] + bi[o]);
        float obv = ob[o];
        Z += e;
        pd = fmaf(e, obv, pd);
        eo = fmaf(em[o], obv, eo);
      }
      ws[OFF_LEPP + (size_t)m*Gn + g] = __logf((1.f-EMISS_W)*eo + EMISS_W*(pd/Z));
    }
  }
}

// ---------------- forward/backward recursions: chunked with warm-up ----------
// Serial depth 40 (FBW warm-up + FBL chunk). Stages exp(sum of 4 lep
// partials) straight from OFF_LEPP (lep_reduce kernel deleted).
constexpr int FBW = 24;   // warm-up steps
constexpr int FBL = 16;   // chunk length

__global__ __launch_bounds__(64) void fb_kernel(float* __restrict__ ws){
  __shared__ __align__(16) float ldsE[(FBW+FBL)*48];   // exp(lep) window
  __shared__ __align__(16) float ring[2][64];
  const int lane = threadIdx.x;
  const int c    = blockIdx.x;
  const int b    = blockIdx.y;
  const bool fwd = blockIdx.z == 0;
  const bool act = lane < Hn;
  const int t0 = c*FBL, te = t0 + FBL - 1;

  float pt[Hn];
#pragma unroll
  for (int i = 0; i < Hn; ++i)
    pt[i] = act ? (fwd ? ws[OFF_PT + i*Hn + lane] : ws[OFF_PT + lane*Hn + i]) : 0.f;

  int row_lo, nrows, sA, sZ;
  bool exact;
  if (fwd){
    sA = t0 - FBW;
    exact = (sA < 1);
    row_lo = exact ? 0 : sA;
    if (exact) sA = 1;
    sZ = te;
    nrows = te - row_lo + 1;
  } else {
    int th = te + 1 + FBW;
    exact = (th > Tn - 2);
    sA = exact ? Tn - 2 : th - 1;
    sZ = t0;
    row_lo = t0;
    nrows = sA - t0 + 1;
  }

  // stage exp(lep) = exp(sum of 4 partials) from [m][192] layout
  {
    const float* src = ws + OFF_LEPP + ((size_t)b*Tn + row_lo)*Gn;
    int n4 = nrows * (Hn/4);
    for (int i = lane; i < n4; i += 64){
      int r = i / (Hn/4), h4 = i - r*(Hn/4);
      const float* p = src + (size_t)r*Gn + h4*4;
      float4 a = *(const float4*)(p);
      float4 b2 = *(const float4*)(p + Hn);
      float4 c2 = *(const float4*)(p + 2*Hn);
      float4 d2 = *(const float4*)(p + 3*Hn);
      float4 e;
      e.x = __expf(a.x + b2.x + c2.x + d2.x);
      e.y = __expf(a.y + b2.y + c2.y + d2.y);
      e.z = __expf(a.z + b2.z + c2.z + d2.z);
      e.w = __expf(a.w + b2.w + c2.w + d2.w);
      ((float4*)ldsE)[i] = e;
    }
  }
  __syncthreads();

  if (fwd){
    const size_t laF = OFF_LA + (size_t)b * Tn * Hn;
    float v;
    if (exact){
      v = act ? __expf(ws[OFF_LP + lane]) * ldsE[lane] : 0.f;   // alpha_0
      if (c == 0 && act) ws[laF + lane] = v;
    } else {
      v = act ? 1.f : 0.f;
    }
    if (act) ring[0][lane] = v;
    __syncthreads();
    int cur = 0;
    for (int t = sA; t <= sZ; ++t){
      float S = waveSum(v);
      const float* rp = ring[cur];
      float s0=0.f,s1=0.f,s2=0.f,s3=0.f;
#pragma unroll
      for (int i = 0; i < Hn; i += 4){
        float4 a = *(const float4*)(rp + i);
        s0 = fmaf(a.x, pt[i+0], s0); s1 = fmaf(a.y, pt[i+1], s1);
        s2 = fmaf(a.z, pt[i+2], s2); s3 = fmaf(a.w, pt[i+3], s3);
      }
      float sd = (s0+s1)+(s2+s3);
      float e = act ? ldsE[(t - row_lo)*Hn + lane] : 0.f;
      float vn = act ? e * sd * (1.f/S) : 0.f;
      cur ^= 1;
      if (act) ring[cur][lane] = vn;
      __syncthreads();
      if (act && t >= t0) ws[laF + (size_t)t*Hn + lane] = vn;
      v = vn;
    }
  } else {
    const size_t lbF = OFF_LB + (size_t)b * Tn * Hn;
    float v = act ? 1.f : 0.f;
    if (exact && c == (Tn/FBL - 1) && act) ws[lbF + (size_t)(Tn-1)*Hn + lane] = 1.f;
    int cur = 0;
    for (int t = sA; t >= sZ; --t){
      float e = act ? ldsE[(t - row_lo)*Hn + lane] : 0.f;
      float wv = e * v;
      if (act) ring[cur][lane] = wv;
      float S = waveSum(wv);
      __syncthreads();
      const float* rp = ring[cur];
      float s0=0.f,s1=0.f,s2=0.f,s3=0.f;
#pragma unroll
      for (int j = 0; j < Hn; j += 4){
        float4 a = *(const float4*)(rp + j);
        s0 = fmaf(a.x, pt[j+0], s0); s1 = fmaf(a.y, pt[j+1], s1);
        s2 = fmaf(a.z, pt[j+2], s2); s3 = fmaf(a.w, pt[j+3], s3);
      }
      float vn = act ? ((s0+s1)+(s2+s3)) * (1.f/S) : 0.f;
      cur ^= 1;
      if (act && t <= te) ws[lbF + (size_t)t*Hn + lane] = vn;
      v = vn;
    }
  }
}

// -------- gamma / xi / masked accumulation (prob domain, no atomics) -----------
// One coalesced partial store per block; sum_kernel reduces. (R9's last-block
// counter pattern = 8192 serialized same-address atomics+fences = 165us. Never
// funnel per-block completion through one address on this chip.)
__global__ __launch_bounds__(256) void gamma_xi_kernel(
    const float* __restrict__ ws_c, float* __restrict__ ws,
    const int* __restrict__ seq_len){
  __shared__ float y_s[Hn], lap_s[Hn];
  __shared__ float red[8];
  const int tid = threadIdx.x;
  const int bid = blockIdx.x;
  const int b = bid >> 9, t = bid & (Tn-1);
  const int len = seq_len[b];
  int tb = t + (Tn - len); if (tb >= Tn) tb -= Tn;
  const size_t bt = (size_t)b*Tn + t;
  float lep = 0.f;
  if (tid < Hn){
    const float* lpp = ws_c + OFF_LEPP + bt*Gn + tid;
    lep = lpp[0] + lpp[Hn] + lpp[2*Hn] + lpp[3*Hn];
    float lb  = ws_c[OFF_LB + ((size_t)b*Tn + tb)*Hn + tid];
    y_s[tid] = __expf(lep) * lb;
    if (t >= 1) lap_s[tid] = ws_c[OFF_LA + (bt-1)*Hn + tid];
  }
  float emis_term = 0.f, prior_term = 0.f;
  if (tid < 64){
    int h = (tid < Hn) ? tid : 0;
    float la  = ws_c[OFF_LA + bt*Hn + h];
    float lb  = ws_c[OFF_LB + ((size_t)b*Tn + tb)*Hn + h];
    float lp  = ws_c[OFF_LP + h];
    float wgt = (tid < Hn) ? la*lb : 0.f;
    float Z = waveSum(wgt);
    float inv = 1.f / Z;
    emis_term  = waveSum(wgt * lep) * inv;
    prior_term = waveSum(wgt * lp) * inv;
  }
  __syncthreads();
  float tran_term = 0.f;
  if (t >= 1){
    float se = 0.f, st = 0.f;
#pragma unroll
    for (int k=0;k<9;++k){
      int e = tid + k*256;
      int i = e / Hn, j = e - i*Hn;
      float e2 = ws_c[OFF_PT + e] * lap_s[i] * y_s[j];
      se += e2;
      st = fmaf(e2, ws_c[OFF_LT + e], st);
    }
    se = waveSum(se);
    st = waveSum(st);
    const int wid = tid >> 6;
    if ((tid & 63) == 0){ red[wid] = se; red[4+wid] = st; }
    __syncthreads();
    if (tid == 0){
      float SE = red[0]+red[1]+red[2]+red[3];
      float ST = red[4]+red[5]+red[6]+red[7];
      tran_term = ST / SE;
    }
  }
  if (tid == 0){
    float tot = 0.f;
    if (t < len)            tot += emis_term;
    if (t == 0)             tot += prior_term;
    if (t >= 1 && t < len)  tot += tran_term;
    ws[OFF_RED + bid] = tot;
  }
}

// ---------------- final reduction: 8192 partials -> scalar ---------------------
__global__ __launch_bounds__(256) void sum_kernel(const float* __restrict__ ws,
                                                  float* __restrict__ out){
  __shared__ float red[4];
  const int tid = threadIdx.x;
  float s = 0.f;
  for (int i = tid; i < Mn; i += 256) s += ws[OFF_RED + i];
  s = waveSum(s);
  if ((tid & 63) == 0) red[tid >> 6] = s;
  __syncthreads();
  if (tid == 0) out[0] = (red[0]+red[1]+red[2]+red[3]) * (1.f / Bn);
}

} // namespace

extern "C" void kernel_launch(void* const* d_in, const int* in_sizes, int n_in,
                              void* d_out, int out_size, void* d_ws, size_t ws_size,
                              hipStream_t stream){
  const float* emb = (const float*)d_in[0];
  const float* obs = (const float*)d_in[1];
  const float* sp  = (const float*)d_in[2];
  const float* ut  = (const float*)d_in[3];
  const float* ue  = (const float*)d_in[4];
  const float* Wm  = (const float*)d_in[5];
  const float* bm  = (const float*)d_in[6];
  const int*   sl  = (const int*)d_in[7];
  float* ws  = (float*)d_ws;
  float* out = (float*)d_out;
  (void)in_sizes; (void)n_in; (void)ws_size; (void)out_size;

  unsigned short* embB = (unsigned short*)(ws + FLOATS_END);
  unsigned short* WB   = embB + (size_t)Mn * Dn;

  const int n4a = Mn*Dn/4, n4b = Nn*Dn/4;
  const int nconv = (n4a + n4b + 255)/256;
  convprep_kernel<<<nconv + 1, 256, 0, stream>>>(emb, embB, n4a, Wm, WB, n4b,
                                                 sp, ut, ue, ws, nconv);
  gemm_lep_kernel<<<dim3(Mn/BM, Nn/BN), 512, 0, stream>>>(embB, WB, bm, obs, ws);
  fb_kernel<<<dim3(Tn/FBL, Bn, 2), 64, 0, stream>>>(ws);
  gamma_xi_kernel<<<Bn*Tn, 256, 0, stream>>>(ws, ws, sl);
  sum_kernel<<<1, 256, 0, stream>>>(ws, out);
}